// Round 1
// baseline (189.832 us; speedup 1.0000x reference)
//
#include <hip/hip_runtime.h>
#include <hip/hip_bf16.h>

// Problem constants (from reference):
//   B=4, N=2048, F_IN=32, D=64; gat1 heads=4 d=32 (out 128); gat2 heads=1 d=64.
#define BB 4
#define NN 2048
#define FIN 32
#define DD 64
#define MAXDEG 256   // binomial(2048, 0.02): mean 41, std 6.3 -> 256 is >30 sigma

// ---------------------------------------------------------------------------
// CSR build: ordered, deterministic compaction of nonzero columns per row.
// One wave (64 lanes) per row; ballot+popcount keeps ascending order (no atomics).
__global__ __launch_bounds__(64) void build_csr(const float* __restrict__ adj,
                                                int* __restrict__ deg,
                                                int* __restrict__ col) {
    const int i = blockIdx.x;
    const int lane = threadIdx.x;           // 0..63
    int base = 0;
    for (int j0 = 0; j0 < NN; j0 += 64) {
        const int j = j0 + lane;
        const bool nz = adj[(size_t)i * NN + j] != 0.0f;
        const unsigned long long m = __ballot(nz);
        const int before = __popcll(m & ((1ull << lane) - 1ull));
        if (nz) {
            const int slot = base + before;
            if (slot < MAXDEG) col[i * MAXDEG + slot] = j;
        }
        base += __popcll(m);
    }
    if (lane == 0) deg[i] = base < MAXDEG ? base : MAXDEG;
}

// ---------------------------------------------------------------------------
// Row-wise GEMM: Y[row, :] = X[row, :K] @ W[K, Ncols] + bias.  One block per row.
// X row staged in LDS; W reads coalesced across threads and L2-resident (<=64KB).
__global__ __launch_bounds__(128) void gemm_rowwise(const float* __restrict__ X,
                                                    const float* __restrict__ W,
                                                    const float* __restrict__ bias,
                                                    float* __restrict__ Y,
                                                    int K, int Ncols) {
    const int row = blockIdx.x;
    const int tid = threadIdx.x;
    __shared__ float xs[128];
    for (int k = tid; k < K; k += 128) xs[k] = X[(size_t)row * K + k];
    __syncthreads();
    for (int c = tid; c < Ncols; c += 128) {
        float acc = bias[c];
        for (int k = 0; k < K; ++k) acc = fmaf(xs[k], W[(size_t)k * Ncols + c], acc);
        Y[(size_t)row * Ncols + c] = acc;
    }
}

// ---------------------------------------------------------------------------
// gat1 attention (heads=4, d=32) + ReLU.  One 128-thread block per (b,i);
// thread t handles column t = h*32+dd.  Online softmax over the sparse
// neighbor list; 32-lane butterfly reduces the per-head dot products.
__global__ __launch_bounds__(128) void attn1_relu(const float* __restrict__ q1,
                                                  const float* __restrict__ k1,
                                                  const float* __restrict__ v1,
                                                  const int* __restrict__ deg,
                                                  const int* __restrict__ col,
                                                  float* __restrict__ h) {
    const int bi = blockIdx.x;
    const int b = bi / NN, i = bi % NN;
    const int tid = threadIdx.x;            // 0..127 = h*32+dd

    __shared__ int nbr[MAXDEG];
    __shared__ int sdeg;
    if (tid == 0) sdeg = deg[i];
    __syncthreads();
    const int d = sdeg;
    for (int s = tid; s < d; s += 128) nbr[s] = col[i * MAXDEG + s];
    __syncthreads();

    const size_t base = (size_t)b * NN * 128;
    const float qv = q1[base + (size_t)i * 128 + tid];
    const float scale = 0.17677669529663687f;   // 1/sqrt(32)

    float m = -INFINITY, ssum = 0.0f, acc = 0.0f;
    for (int t = 0; t < d; ++t) {
        const int j = nbr[t];
        float p = qv * k1[base + (size_t)j * 128 + tid];
        p += __shfl_xor(p, 16);
        p += __shfl_xor(p, 8);
        p += __shfl_xor(p, 4);
        p += __shfl_xor(p, 2);
        p += __shfl_xor(p, 1);
        const float sc = p * scale;
        const float nm = fmaxf(m, sc);
        const float w  = __expf(sc - nm);
        const float cf = __expf(m - nm);    // exp(-inf)=0 on first iter
        ssum = ssum * cf + w;
        acc  = acc * cf + w * v1[base + (size_t)j * 128 + tid];
        m = nm;
    }
    float out;
    if (d > 0) {
        out = acc / ssum;
    } else {
        // empty row: mask is -1e9 everywhere -> uniform softmax over all j
        float a = 0.0f;
        for (int j = 0; j < NN; ++j) a += v1[base + (size_t)j * 128 + tid];
        out = a * (1.0f / NN);
    }
    h[base + (size_t)i * 128 + tid] = fmaxf(out, 0.0f);
}

// ---------------------------------------------------------------------------
// gat2 attention (heads=1, d=64) + residual + LayerNorm.  One wave per (b,i).
__global__ __launch_bounds__(64) void attn2_ln(const float* __restrict__ q2,
                                               const float* __restrict__ k2,
                                               const float* __restrict__ v2,
                                               const float* __restrict__ proj,
                                               const int* __restrict__ deg,
                                               const int* __restrict__ col,
                                               const float* __restrict__ gamma,
                                               const float* __restrict__ beta,
                                               float* __restrict__ out) {
    const int bi = blockIdx.x;
    const int b = bi / NN, i = bi % NN;
    const int dd = threadIdx.x;             // 0..63

    __shared__ int nbr[MAXDEG];
    __shared__ int sdeg;
    if (dd == 0) sdeg = deg[i];
    __syncthreads();
    const int d = sdeg;
    for (int s = dd; s < d; s += 64) nbr[s] = col[i * MAXDEG + s];
    __syncthreads();

    const size_t base = (size_t)b * NN * 64;
    const float qv = q2[base + (size_t)i * 64 + dd];
    const float scale = 0.125f;             // 1/sqrt(64)

    float m = -INFINITY, ssum = 0.0f, acc = 0.0f;
    for (int t = 0; t < d; ++t) {
        const int j = nbr[t];
        float p = qv * k2[base + (size_t)j * 64 + dd];
        p += __shfl_xor(p, 32);
        p += __shfl_xor(p, 16);
        p += __shfl_xor(p, 8);
        p += __shfl_xor(p, 4);
        p += __shfl_xor(p, 2);
        p += __shfl_xor(p, 1);
        const float sc = p * scale;
        const float nm = fmaxf(m, sc);
        const float w  = __expf(sc - nm);
        const float cf = __expf(m - nm);
        ssum = ssum * cf + w;
        acc  = acc * cf + w * v2[base + (size_t)j * 64 + dd];
        m = nm;
    }
    float att;
    if (d > 0) {
        att = acc / ssum;
    } else {
        float a = 0.0f;
        for (int j = 0; j < NN; ++j) a += v2[base + (size_t)j * 64 + dd];
        att = a * (1.0f / NN);
    }

    // y = attn_out + proj; LayerNorm over the 64 lanes
    float y = att + proj[base + (size_t)i * 64 + dd];
    float s = y;
    s += __shfl_xor(s, 32); s += __shfl_xor(s, 16); s += __shfl_xor(s, 8);
    s += __shfl_xor(s, 4);  s += __shfl_xor(s, 2);  s += __shfl_xor(s, 1);
    const float mu = s * (1.0f / 64.0f);
    const float yc = y - mu;
    float sq = yc * yc;
    sq += __shfl_xor(sq, 32); sq += __shfl_xor(sq, 16); sq += __shfl_xor(sq, 8);
    sq += __shfl_xor(sq, 4);  sq += __shfl_xor(sq, 2);  sq += __shfl_xor(sq, 1);
    const float var = sq * (1.0f / 64.0f);
    out[base + (size_t)i * 64 + dd] = gamma[dd] * yc * rsqrtf(var + 1e-6f) + beta[dd];
}

// ---------------------------------------------------------------------------
extern "C" void kernel_launch(void* const* d_in, const int* in_sizes, int n_in,
                              void* d_out, int out_size, void* d_ws, size_t ws_size,
                              hipStream_t stream) {
    const float* x     = (const float*)d_in[0];
    const float* adj   = (const float*)d_in[1];
    const float* Wp    = (const float*)d_in[2];
    const float* bp    = (const float*)d_in[3];
    const float* Wq1   = (const float*)d_in[4];
    const float* bq1   = (const float*)d_in[5];
    const float* Wk1   = (const float*)d_in[6];
    const float* bk1   = (const float*)d_in[7];
    const float* Wv1   = (const float*)d_in[8];
    const float* bv1   = (const float*)d_in[9];
    const float* Wq2   = (const float*)d_in[10];
    const float* bq2   = (const float*)d_in[11];
    const float* Wk2   = (const float*)d_in[12];
    const float* bk2   = (const float*)d_in[13];
    const float* Wv2   = (const float*)d_in[14];
    const float* bv2   = (const float*)d_in[15];
    const float* gamma = (const float*)d_in[16];
    const float* beta  = (const float*)d_in[17];
    float* out = (float*)d_out;

    char* ws = (char*)d_ws;
    size_t off = 0;
    auto alloc = [&](size_t bytes) {
        void* p = ws + off;
        off = (off + bytes + 255) & ~(size_t)255;
        return p;
    };
    int*   deg  = (int*)  alloc((size_t)NN * 4);
    int*   col  = (int*)  alloc((size_t)NN * MAXDEG * 4);
    float* proj = (float*)alloc((size_t)BB * NN * 64 * 4);
    float* q1   = (float*)alloc((size_t)BB * NN * 128 * 4);
    float* k1   = (float*)alloc((size_t)BB * NN * 128 * 4);
    float* v1   = (float*)alloc((size_t)BB * NN * 128 * 4);
    float* h    = (float*)alloc((size_t)BB * NN * 128 * 4);
    float* q2   = (float*)alloc((size_t)BB * NN * 64 * 4);
    float* k2   = (float*)alloc((size_t)BB * NN * 64 * 4);
    float* v2   = (float*)alloc((size_t)BB * NN * 64 * 4);

    const int BN = BB * NN;

    build_csr<<<NN, 64, 0, stream>>>(adj, deg, col);

    gemm_rowwise<<<BN, 128, 0, stream>>>(x, Wp,  bp,  proj, FIN, 64);
    gemm_rowwise<<<BN, 128, 0, stream>>>(x, Wq1, bq1, q1,   FIN, 128);
    gemm_rowwise<<<BN, 128, 0, stream>>>(x, Wk1, bk1, k1,   FIN, 128);
    gemm_rowwise<<<BN, 128, 0, stream>>>(x, Wv1, bv1, v1,   FIN, 128);

    attn1_relu<<<BN, 128, 0, stream>>>(q1, k1, v1, deg, col, h);

    gemm_rowwise<<<BN, 128, 0, stream>>>(h, Wq2, bq2, q2, 128, 64);
    gemm_rowwise<<<BN, 128, 0, stream>>>(h, Wk2, bk2, k2, 128, 64);
    gemm_rowwise<<<BN, 128, 0, stream>>>(h, Wv2, bv2, v2, 128, 64);

    attn2_ln<<<BN, 64, 0, stream>>>(q2, k2, v2, proj, deg, col, gamma, beta, out);
}

// Round 2
// 121.517 us; speedup vs baseline: 1.5622x; 1.5622x over previous
//
#include <hip/hip_runtime.h>
#include <hip/hip_bf16.h>

// Problem constants (from reference):
//   B=4, N=2048, F_IN=32, D=64; gat1 heads=4 d=32 (out 128); gat2 heads=1 d=64.
#define BB 4
#define NN 2048
#define FIN 32
#define DD 64
#define MAXDEG 256   // binomial(2048, 0.02): mean 41, std 6.3 -> 256 is >30 sigma

// ---------------------------------------------------------------------------
// CSR build: ordered deterministic compaction. One wave per row, float4 loads,
// 4 ballots per iteration (8 iterations total). Order = ascending j.
__global__ __launch_bounds__(64) void build_csr(const float* __restrict__ adj,
                                                int* __restrict__ deg,
                                                int* __restrict__ col) {
    const int i = blockIdx.x;
    const int lane = threadIdx.x;           // 0..63
    const unsigned long long below = (1ull << lane) - 1ull;
    int base = 0;
    for (int j0 = 0; j0 < NN; j0 += 256) {
        const float4 a = *(const float4*)(adj + (size_t)i * NN + j0 + lane * 4);
        const bool n0 = a.x != 0.0f, n1 = a.y != 0.0f, n2 = a.z != 0.0f, n3 = a.w != 0.0f;
        const unsigned long long m0 = __ballot(n0);
        const unsigned long long m1 = __ballot(n1);
        const unsigned long long m2 = __ballot(n2);
        const unsigned long long m3 = __ballot(n3);
        // j = j0 + 4*lane + s; ascending order = (lane, s) lexicographic
        int slot = base + __popcll(m0 & below) + __popcll(m1 & below)
                        + __popcll(m2 & below) + __popcll(m3 & below);
        const int jb = j0 + 4 * lane;
        if (n0) { if (slot < MAXDEG) col[i * MAXDEG + slot] = jb;     ++slot; }
        if (n1) { if (slot < MAXDEG) col[i * MAXDEG + slot] = jb + 1; ++slot; }
        if (n2) { if (slot < MAXDEG) col[i * MAXDEG + slot] = jb + 2; ++slot; }
        if (n3) { if (slot < MAXDEG) col[i * MAXDEG + slot] = jb + 3; ++slot; }
        base += __popcll(m0) + __popcll(m1) + __popcll(m2) + __popcll(m3);
    }
    if (lane == 0) deg[i] = base < MAXDEG ? base : MAXDEG;
}

// ---------------------------------------------------------------------------
// Fused K=32 GEMMs: proj(64) + q1/k1/v1(128 each). 4 rows per block, 128 thr.
// x rows staged transposed in LDS (float4 broadcast reads); W reused across
// 4 rows in registers -> 12 independent FMA chains.
__global__ __launch_bounds__(128) void gemm1_fused(const float* __restrict__ x,
    const float* __restrict__ Wp, const float* __restrict__ bp,
    const float* __restrict__ Wq, const float* __restrict__ bq,
    const float* __restrict__ Wk, const float* __restrict__ bk,
    const float* __restrict__ Wv, const float* __restrict__ bv,
    float* __restrict__ proj, float* __restrict__ q1,
    float* __restrict__ k1, float* __restrict__ v1) {
    const int r0 = blockIdx.x * 4;
    const int tid = threadIdx.x;
    __shared__ float xs[FIN * 4];           // xs[k*4+r]
    {
        const int r = tid >> 5, k = tid & 31;     // tid = r*32+k, coalesced read
        xs[k * 4 + r] = x[(size_t)r0 * FIN + tid];
    }
    __syncthreads();

    float aq0 = bq[tid], aq1 = aq0, aq2 = aq0, aq3 = aq0;
    float ak0 = bk[tid], ak1 = ak0, ak2 = ak0, ak3 = ak0;
    float av0 = bv[tid], av1 = av0, av2 = av0, av3 = av0;
    #pragma unroll
    for (int k = 0; k < FIN; ++k) {
        const float wq = Wq[k * 128 + tid];
        const float wk = Wk[k * 128 + tid];
        const float wv = Wv[k * 128 + tid];
        const float4 xv = *(const float4*)&xs[k * 4];
        aq0 = fmaf(xv.x, wq, aq0); aq1 = fmaf(xv.y, wq, aq1);
        aq2 = fmaf(xv.z, wq, aq2); aq3 = fmaf(xv.w, wq, aq3);
        ak0 = fmaf(xv.x, wk, ak0); ak1 = fmaf(xv.y, wk, ak1);
        ak2 = fmaf(xv.z, wk, ak2); ak3 = fmaf(xv.w, wk, ak3);
        av0 = fmaf(xv.x, wv, av0); av1 = fmaf(xv.y, wv, av1);
        av2 = fmaf(xv.z, wv, av2); av3 = fmaf(xv.w, wv, av3);
    }
    q1[(size_t)(r0 + 0) * 128 + tid] = aq0; q1[(size_t)(r0 + 1) * 128 + tid] = aq1;
    q1[(size_t)(r0 + 2) * 128 + tid] = aq2; q1[(size_t)(r0 + 3) * 128 + tid] = aq3;
    k1[(size_t)(r0 + 0) * 128 + tid] = ak0; k1[(size_t)(r0 + 1) * 128 + tid] = ak1;
    k1[(size_t)(r0 + 2) * 128 + tid] = ak2; k1[(size_t)(r0 + 3) * 128 + tid] = ak3;
    v1[(size_t)(r0 + 0) * 128 + tid] = av0; v1[(size_t)(r0 + 1) * 128 + tid] = av1;
    v1[(size_t)(r0 + 2) * 128 + tid] = av2; v1[(size_t)(r0 + 3) * 128 + tid] = av3;

    if (tid < 64) {
        float a0 = bp[tid], a1 = a0, a2 = a0, a3 = a0;
        #pragma unroll
        for (int k = 0; k < FIN; ++k) {
            const float wp = Wp[k * 64 + tid];
            const float4 xv = *(const float4*)&xs[k * 4];
            a0 = fmaf(xv.x, wp, a0); a1 = fmaf(xv.y, wp, a1);
            a2 = fmaf(xv.z, wp, a2); a3 = fmaf(xv.w, wp, a3);
        }
        proj[(size_t)(r0 + 0) * 64 + tid] = a0; proj[(size_t)(r0 + 1) * 64 + tid] = a1;
        proj[(size_t)(r0 + 2) * 64 + tid] = a2; proj[(size_t)(r0 + 3) * 64 + tid] = a3;
    }
}

// ---------------------------------------------------------------------------
// Fused K=128 GEMMs: q2/k2/v2 (64 cols each). 8 rows per block, 192 threads
// (wave w handles matrix w). W value reused across 8 rows in registers.
__global__ __launch_bounds__(192) void gemm2_fused(const float* __restrict__ h,
    const float* __restrict__ Wq, const float* __restrict__ bq,
    const float* __restrict__ Wk, const float* __restrict__ bk,
    const float* __restrict__ Wv, const float* __restrict__ bv,
    float* __restrict__ q2, float* __restrict__ k2, float* __restrict__ v2) {
    const int r0 = blockIdx.x * 8;
    const int tid = threadIdx.x;
    const int mat = tid / 64;               // wave-uniform
    const int c = tid & 63;
    __shared__ float xs[128][8];            // xs[k][r]
    for (int idx = tid; idx < 8 * 128; idx += 192) {
        const int r = idx >> 7, k = idx & 127;
        xs[k][r] = h[(size_t)r0 * 128 + idx];
    }
    __syncthreads();

    const float* __restrict__ W   = mat == 0 ? Wq : (mat == 1 ? Wk : Wv);
    const float* __restrict__ bia = mat == 0 ? bq : (mat == 1 ? bk : bv);
    float* __restrict__ Y         = mat == 0 ? q2 : (mat == 1 ? k2 : v2);

    float acc[8];
    const float b0 = bia[c];
    #pragma unroll
    for (int r = 0; r < 8; ++r) acc[r] = b0;
    #pragma unroll 4
    for (int k = 0; k < 128; ++k) {
        const float w = W[(size_t)k * 64 + c];
        const float4 xa = *(const float4*)&xs[k][0];
        const float4 xb = *(const float4*)&xs[k][4];
        acc[0] = fmaf(xa.x, w, acc[0]); acc[1] = fmaf(xa.y, w, acc[1]);
        acc[2] = fmaf(xa.z, w, acc[2]); acc[3] = fmaf(xa.w, w, acc[3]);
        acc[4] = fmaf(xb.x, w, acc[4]); acc[5] = fmaf(xb.y, w, acc[5]);
        acc[6] = fmaf(xb.z, w, acc[6]); acc[7] = fmaf(xb.w, w, acc[7]);
    }
    #pragma unroll
    for (int r = 0; r < 8; ++r) Y[(size_t)(r0 + r) * 64 + c] = acc[r];
}

// ---------------------------------------------------------------------------
// gat1 attention (heads=4, d=32) + ReLU. One block per node i, ALL 4 batches
// per thread (shared neighbor list) + neighbor-unroll x2 = 8 independent
// reduction chains. tid = h*32+dd.
__global__ __launch_bounds__(128) void attn1_relu(const float* __restrict__ q1,
                                                  const float* __restrict__ k1,
                                                  const float* __restrict__ v1,
                                                  const int* __restrict__ deg,
                                                  const int* __restrict__ col,
                                                  float* __restrict__ h) {
    const int i = blockIdx.x;
    const int tid = threadIdx.x;

    __shared__ int nbr[MAXDEG];
    __shared__ int sdeg;
    if (tid == 0) sdeg = deg[i];
    __syncthreads();
    const int d = sdeg;
    for (int s = tid; s < d; s += 128) nbr[s] = col[i * MAXDEG + s];
    __syncthreads();

    const size_t stride = (size_t)NN * 128;
    const float scale = 0.17677669529663687f;   // 1/sqrt(32)

    float qv[BB], m[BB], ssum[BB], acc[BB];
    #pragma unroll
    for (int b = 0; b < BB; ++b) {
        qv[b] = q1[b * stride + (size_t)i * 128 + tid];
        m[b] = -INFINITY; ssum[b] = 0.0f; acc[b] = 0.0f;
    }

    int t = 0;
    for (; t + 2 <= d; t += 2) {
        const int ja = nbr[t], jb = nbr[t + 1];
        float pa[BB], pb[BB], va[BB], vb[BB];
        #pragma unroll
        for (int b = 0; b < BB; ++b) {
            pa[b] = qv[b] * k1[b * stride + (size_t)ja * 128 + tid];
            pb[b] = qv[b] * k1[b * stride + (size_t)jb * 128 + tid];
            va[b] = v1[b * stride + (size_t)ja * 128 + tid];
            vb[b] = v1[b * stride + (size_t)jb * 128 + tid];
        }
        #pragma unroll
        for (int off = 16; off >= 1; off >>= 1) {
            #pragma unroll
            for (int b = 0; b < BB; ++b) {
                pa[b] += __shfl_xor(pa[b], off);
                pb[b] += __shfl_xor(pb[b], off);
            }
        }
        #pragma unroll
        for (int b = 0; b < BB; ++b) {
            const float sa = pa[b] * scale, sb = pb[b] * scale;
            const float nm = fmaxf(m[b], fmaxf(sa, sb));
            const float wa = __expf(sa - nm), wb = __expf(sb - nm);
            const float cf = __expf(m[b] - nm);
            ssum[b] = ssum[b] * cf + wa + wb;
            acc[b]  = acc[b]  * cf + wa * va[b] + wb * vb[b];
            m[b] = nm;
        }
    }
    if (t < d) {
        const int j = nbr[t];
        float p[BB], vv[BB];
        #pragma unroll
        for (int b = 0; b < BB; ++b) {
            p[b] = qv[b] * k1[b * stride + (size_t)j * 128 + tid];
            vv[b] = v1[b * stride + (size_t)j * 128 + tid];
        }
        #pragma unroll
        for (int off = 16; off >= 1; off >>= 1) {
            #pragma unroll
            for (int b = 0; b < BB; ++b) p[b] += __shfl_xor(p[b], off);
        }
        #pragma unroll
        for (int b = 0; b < BB; ++b) {
            const float sc = p[b] * scale;
            const float nm = fmaxf(m[b], sc);
            const float w  = __expf(sc - nm);
            const float cf = __expf(m[b] - nm);
            ssum[b] = ssum[b] * cf + w;
            acc[b]  = acc[b]  * cf + w * vv[b];
            m[b] = nm;
        }
    }
    #pragma unroll
    for (int b = 0; b < BB; ++b) {
        float o;
        if (d > 0) {
            o = acc[b] / ssum[b];
        } else {
            float a = 0.0f;
            for (int j = 0; j < NN; ++j) a += v1[b * stride + (size_t)j * 128 + tid];
            o = a * (1.0f / NN);
        }
        h[b * stride + (size_t)i * 128 + tid] = fmaxf(o, 0.0f);
    }
}

// ---------------------------------------------------------------------------
// gat2 attention (heads=1, d=64) + residual + LayerNorm. One wave per node,
// all 4 batches per thread, neighbor-unroll x2.
__global__ __launch_bounds__(64) void attn2_ln(const float* __restrict__ q2,
                                               const float* __restrict__ k2,
                                               const float* __restrict__ v2,
                                               const float* __restrict__ proj,
                                               const int* __restrict__ deg,
                                               const int* __restrict__ col,
                                               const float* __restrict__ gamma,
                                               const float* __restrict__ beta,
                                               float* __restrict__ out) {
    const int i = blockIdx.x;
    const int dd = threadIdx.x;             // 0..63

    __shared__ int nbr[MAXDEG];
    __shared__ int sdeg;
    if (dd == 0) sdeg = deg[i];
    __syncthreads();
    const int d = sdeg;
    for (int s = dd; s < d; s += 64) nbr[s] = col[i * MAXDEG + s];
    __syncthreads();

    const size_t stride = (size_t)NN * 64;
    const float scale = 0.125f;             // 1/sqrt(64)

    float qv[BB], m[BB], ssum[BB], acc[BB];
    #pragma unroll
    for (int b = 0; b < BB; ++b) {
        qv[b] = q2[b * stride + (size_t)i * 64 + dd];
        m[b] = -INFINITY; ssum[b] = 0.0f; acc[b] = 0.0f;
    }

    int t = 0;
    for (; t + 2 <= d; t += 2) {
        const int ja = nbr[t], jb = nbr[t + 1];
        float pa[BB], pb[BB], va[BB], vb[BB];
        #pragma unroll
        for (int b = 0; b < BB; ++b) {
            pa[b] = qv[b] * k2[b * stride + (size_t)ja * 64 + dd];
            pb[b] = qv[b] * k2[b * stride + (size_t)jb * 64 + dd];
            va[b] = v2[b * stride + (size_t)ja * 64 + dd];
            vb[b] = v2[b * stride + (size_t)jb * 64 + dd];
        }
        #pragma unroll
        for (int off = 32; off >= 1; off >>= 1) {
            #pragma unroll
            for (int b = 0; b < BB; ++b) {
                pa[b] += __shfl_xor(pa[b], off);
                pb[b] += __shfl_xor(pb[b], off);
            }
        }
        #pragma unroll
        for (int b = 0; b < BB; ++b) {
            const float sa = pa[b] * scale, sb = pb[b] * scale;
            const float nm = fmaxf(m[b], fmaxf(sa, sb));
            const float wa = __expf(sa - nm), wb = __expf(sb - nm);
            const float cf = __expf(m[b] - nm);
            ssum[b] = ssum[b] * cf + wa + wb;
            acc[b]  = acc[b]  * cf + wa * va[b] + wb * vb[b];
            m[b] = nm;
        }
    }
    if (t < d) {
        const int j = nbr[t];
        float p[BB], vv[BB];
        #pragma unroll
        for (int b = 0; b < BB; ++b) {
            p[b] = qv[b] * k2[b * stride + (size_t)j * 64 + dd];
            vv[b] = v2[b * stride + (size_t)j * 64 + dd];
        }
        #pragma unroll
        for (int off = 32; off >= 1; off >>= 1) {
            #pragma unroll
            for (int b = 0; b < BB; ++b) p[b] += __shfl_xor(p[b], off);
        }
        #pragma unroll
        for (int b = 0; b < BB; ++b) {
            const float sc = p[b] * scale;
            const float nm = fmaxf(m[b], sc);
            const float w  = __expf(sc - nm);
            const float cf = __expf(m[b] - nm);
            ssum[b] = ssum[b] * cf + w;
            acc[b]  = acc[b]  * cf + w * vv[b];
            m[b] = nm;
        }
    }

    const float g = gamma[dd], be = beta[dd];
    #pragma unroll
    for (int b = 0; b < BB; ++b) {
        float att;
        if (d > 0) {
            att = acc[b] / ssum[b];
        } else {
            float a = 0.0f;
            for (int j = 0; j < NN; ++j) a += v2[b * stride + (size_t)j * 64 + dd];
            att = a * (1.0f / NN);
        }
        const float y = att + proj[b * stride + (size_t)i * 64 + dd];
        float s = y;
        s += __shfl_xor(s, 32); s += __shfl_xor(s, 16); s += __shfl_xor(s, 8);
        s += __shfl_xor(s, 4);  s += __shfl_xor(s, 2);  s += __shfl_xor(s, 1);
        const float mu = s * (1.0f / 64.0f);
        const float yc = y - mu;
        float sq = yc * yc;
        sq += __shfl_xor(sq, 32); sq += __shfl_xor(sq, 16); sq += __shfl_xor(sq, 8);
        sq += __shfl_xor(sq, 4);  sq += __shfl_xor(sq, 2);  sq += __shfl_xor(sq, 1);
        const float var = sq * (1.0f / 64.0f);
        out[b * stride + (size_t)i * 64 + dd] = g * yc * rsqrtf(var + 1e-6f) + be;
    }
}

// ---------------------------------------------------------------------------
extern "C" void kernel_launch(void* const* d_in, const int* in_sizes, int n_in,
                              void* d_out, int out_size, void* d_ws, size_t ws_size,
                              hipStream_t stream) {
    const float* x     = (const float*)d_in[0];
    const float* adj   = (const float*)d_in[1];
    const float* Wp    = (const float*)d_in[2];
    const float* bp    = (const float*)d_in[3];
    const float* Wq1   = (const float*)d_in[4];
    const float* bq1   = (const float*)d_in[5];
    const float* Wk1   = (const float*)d_in[6];
    const float* bk1   = (const float*)d_in[7];
    const float* Wv1   = (const float*)d_in[8];
    const float* bv1   = (const float*)d_in[9];
    const float* Wq2   = (const float*)d_in[10];
    const float* bq2   = (const float*)d_in[11];
    const float* Wk2   = (const float*)d_in[12];
    const float* bk2   = (const float*)d_in[13];
    const float* Wv2   = (const float*)d_in[14];
    const float* bv2   = (const float*)d_in[15];
    const float* gamma = (const float*)d_in[16];
    const float* beta  = (const float*)d_in[17];
    float* out = (float*)d_out;

    char* ws = (char*)d_ws;
    size_t off = 0;
    auto alloc = [&](size_t bytes) {
        void* p = ws + off;
        off = (off + bytes + 255) & ~(size_t)255;
        return p;
    };
    int*   deg  = (int*)  alloc((size_t)NN * 4);
    int*   col  = (int*)  alloc((size_t)NN * MAXDEG * 4);
    float* proj = (float*)alloc((size_t)BB * NN * 64 * 4);
    float* q1   = (float*)alloc((size_t)BB * NN * 128 * 4);
    float* k1   = (float*)alloc((size_t)BB * NN * 128 * 4);
    float* v1   = (float*)alloc((size_t)BB * NN * 128 * 4);
    float* h    = (float*)alloc((size_t)BB * NN * 128 * 4);
    float* q2   = (float*)alloc((size_t)BB * NN * 64 * 4);
    float* k2   = (float*)alloc((size_t)BB * NN * 64 * 4);
    float* v2   = (float*)alloc((size_t)BB * NN * 64 * 4);

    build_csr<<<NN, 64, 0, stream>>>(adj, deg, col);

    gemm1_fused<<<BB * NN / 4, 128, 0, stream>>>(x, Wp, bp, Wq1, bq1, Wk1, bk1,
                                                 Wv1, bv1, proj, q1, k1, v1);

    attn1_relu<<<NN, 128, 0, stream>>>(q1, k1, v1, deg, col, h);

    gemm2_fused<<<BB * NN / 8, 192, 0, stream>>>(h, Wq2, bq2, Wk2, bk2, Wv2, bv2,
                                                 q2, k2, v2);

    attn2_ln<<<NN, 64, 0, stream>>>(q2, k2, v2, proj, deg, col, gamma, beta, out);
}

// Round 3
// 90.157 us; speedup vs baseline: 2.1056x; 1.3478x over previous
//
#include <hip/hip_runtime.h>
#include <hip/hip_bf16.h>

// Problem constants (from reference):
//   B=4, N=2048, F_IN=32, D=64; gat1 heads=4 d=32 (out 128); gat2 heads=1 d=64.
#define BB 4
#define NN 2048
#define FIN 32
#define DD 64
#define MAXDEG 256   // binomial(2048, 0.02): mean 41, std 6.3 -> 256 is >30 sigma

// ---------------------------------------------------------------------------
// CSR build: ordered deterministic compaction. One wave per row, float4 loads,
// 4 ballots per iteration (8 iterations total). Order = ascending j.
__global__ __launch_bounds__(64) void build_csr(const float* __restrict__ adj,
                                                int* __restrict__ deg,
                                                int* __restrict__ col) {
    const int i = blockIdx.x;
    const int lane = threadIdx.x;           // 0..63
    const unsigned long long below = (1ull << lane) - 1ull;
    int base = 0;
    for (int j0 = 0; j0 < NN; j0 += 256) {
        const float4 a = *(const float4*)(adj + (size_t)i * NN + j0 + lane * 4);
        const bool n0 = a.x != 0.0f, n1 = a.y != 0.0f, n2 = a.z != 0.0f, n3 = a.w != 0.0f;
        const unsigned long long m0 = __ballot(n0);
        const unsigned long long m1 = __ballot(n1);
        const unsigned long long m2 = __ballot(n2);
        const unsigned long long m3 = __ballot(n3);
        int slot = base + __popcll(m0 & below) + __popcll(m1 & below)
                        + __popcll(m2 & below) + __popcll(m3 & below);
        const int jb = j0 + 4 * lane;
        if (n0) { if (slot < MAXDEG) col[i * MAXDEG + slot] = jb;     ++slot; }
        if (n1) { if (slot < MAXDEG) col[i * MAXDEG + slot] = jb + 1; ++slot; }
        if (n2) { if (slot < MAXDEG) col[i * MAXDEG + slot] = jb + 2; ++slot; }
        if (n3) { if (slot < MAXDEG) col[i * MAXDEG + slot] = jb + 3; ++slot; }
        base += __popcll(m0) + __popcll(m1) + __popcll(m2) + __popcll(m3);
    }
    if (lane == 0) deg[i] = base < MAXDEG ? base : MAXDEG;
}

// ---------------------------------------------------------------------------
// Fused K=32 GEMMs: proj(64) + q1/k1/v1(128 each). 4 rows per block, 128 thr.
__global__ __launch_bounds__(128) void gemm1_fused(const float* __restrict__ x,
    const float* __restrict__ Wp, const float* __restrict__ bp,
    const float* __restrict__ Wq, const float* __restrict__ bq,
    const float* __restrict__ Wk, const float* __restrict__ bk,
    const float* __restrict__ Wv, const float* __restrict__ bv,
    float* __restrict__ proj, float* __restrict__ q1,
    float* __restrict__ k1, float* __restrict__ v1) {
    const int r0 = blockIdx.x * 4;
    const int tid = threadIdx.x;
    __shared__ float xs[FIN * 4];           // xs[k*4+r]
    {
        const int r = tid >> 5, k = tid & 31;
        xs[k * 4 + r] = x[(size_t)r0 * FIN + tid];
    }
    __syncthreads();

    float aq0 = bq[tid], aq1 = aq0, aq2 = aq0, aq3 = aq0;
    float ak0 = bk[tid], ak1 = ak0, ak2 = ak0, ak3 = ak0;
    float av0 = bv[tid], av1 = av0, av2 = av0, av3 = av0;
    #pragma unroll
    for (int k = 0; k < FIN; ++k) {
        const float wq = Wq[k * 128 + tid];
        const float wk = Wk[k * 128 + tid];
        const float wv = Wv[k * 128 + tid];
        const float4 xv = *(const float4*)&xs[k * 4];
        aq0 = fmaf(xv.x, wq, aq0); aq1 = fmaf(xv.y, wq, aq1);
        aq2 = fmaf(xv.z, wq, aq2); aq3 = fmaf(xv.w, wq, aq3);
        ak0 = fmaf(xv.x, wk, ak0); ak1 = fmaf(xv.y, wk, ak1);
        ak2 = fmaf(xv.z, wk, ak2); ak3 = fmaf(xv.w, wk, ak3);
        av0 = fmaf(xv.x, wv, av0); av1 = fmaf(xv.y, wv, av1);
        av2 = fmaf(xv.z, wv, av2); av3 = fmaf(xv.w, wv, av3);
    }
    q1[(size_t)(r0 + 0) * 128 + tid] = aq0; q1[(size_t)(r0 + 1) * 128 + tid] = aq1;
    q1[(size_t)(r0 + 2) * 128 + tid] = aq2; q1[(size_t)(r0 + 3) * 128 + tid] = aq3;
    k1[(size_t)(r0 + 0) * 128 + tid] = ak0; k1[(size_t)(r0 + 1) * 128 + tid] = ak1;
    k1[(size_t)(r0 + 2) * 128 + tid] = ak2; k1[(size_t)(r0 + 3) * 128 + tid] = ak3;
    v1[(size_t)(r0 + 0) * 128 + tid] = av0; v1[(size_t)(r0 + 1) * 128 + tid] = av1;
    v1[(size_t)(r0 + 2) * 128 + tid] = av2; v1[(size_t)(r0 + 3) * 128 + tid] = av3;

    if (tid < 64) {
        float a0 = bp[tid], a1 = a0, a2 = a0, a3 = a0;
        #pragma unroll
        for (int k = 0; k < FIN; ++k) {
            const float wp = Wp[k * 64 + tid];
            const float4 xv = *(const float4*)&xs[k * 4];
            a0 = fmaf(xv.x, wp, a0); a1 = fmaf(xv.y, wp, a1);
            a2 = fmaf(xv.z, wp, a2); a3 = fmaf(xv.w, wp, a3);
        }
        proj[(size_t)(r0 + 0) * 64 + tid] = a0; proj[(size_t)(r0 + 1) * 64 + tid] = a1;
        proj[(size_t)(r0 + 2) * 64 + tid] = a2; proj[(size_t)(r0 + 3) * 64 + tid] = a3;
    }
}

// ---------------------------------------------------------------------------
// Fused K=128 GEMMs: q2/k2/v2 (64 cols each). 8 rows per block, 192 threads.
__global__ __launch_bounds__(192) void gemm2_fused(const float* __restrict__ h,
    const float* __restrict__ Wq, const float* __restrict__ bq,
    const float* __restrict__ Wk, const float* __restrict__ bk,
    const float* __restrict__ Wv, const float* __restrict__ bv,
    float* __restrict__ q2, float* __restrict__ k2, float* __restrict__ v2) {
    const int r0 = blockIdx.x * 8;
    const int tid = threadIdx.x;
    const int mat = tid / 64;               // wave-uniform
    const int c = tid & 63;
    __shared__ float xs[128][8];            // xs[k][r]
    for (int idx = tid; idx < 8 * 128; idx += 192) {
        const int r = idx >> 7, k = idx & 127;
        xs[k][r] = h[(size_t)r0 * 128 + idx];
    }
    __syncthreads();

    const float* __restrict__ W   = mat == 0 ? Wq : (mat == 1 ? Wk : Wv);
    const float* __restrict__ bia = mat == 0 ? bq : (mat == 1 ? bk : bv);
    float* __restrict__ Y         = mat == 0 ? q2 : (mat == 1 ? k2 : v2);

    float acc[8];
    const float b0 = bia[c];
    #pragma unroll
    for (int r = 0; r < 8; ++r) acc[r] = b0;
    #pragma unroll 4
    for (int k = 0; k < 128; ++k) {
        const float w = W[(size_t)k * 64 + c];
        const float4 xa = *(const float4*)&xs[k][0];
        const float4 xb = *(const float4*)&xs[k][4];
        acc[0] = fmaf(xa.x, w, acc[0]); acc[1] = fmaf(xa.y, w, acc[1]);
        acc[2] = fmaf(xa.z, w, acc[2]); acc[3] = fmaf(xa.w, w, acc[3]);
        acc[4] = fmaf(xb.x, w, acc[4]); acc[5] = fmaf(xb.y, w, acc[5]);
        acc[6] = fmaf(xb.z, w, acc[6]); acc[7] = fmaf(xb.w, w, acc[7]);
    }
    #pragma unroll
    for (int r = 0; r < 8; ++r) Y[(size_t)(r0 + r) * 64 + c] = acc[r];
}

// ---------------------------------------------------------------------------
// XCD-aware (b,i) mapping: 8192 blocks; each XCD (bid&7) handles one batch b,
// so the per-XCD L2 holds only that batch's K/V working set.
__device__ __forceinline__ void map_bi(int bid, int& b, int& i) {
    const int xcd = bid & 7;
    const int w = bid >> 3;                 // 0..1023
    b = xcd & 3;
    i = ((xcd >> 2) << 10) | w;
}

// ---------------------------------------------------------------------------
// gat1 attention (heads=4, d=32) + ReLU. Two-phase sparse attention:
//   Phase A: thread=(h, slot) computes a FULL score via lane-local 32-dim dot
//            (no per-neighbor cross-lane reduce). Softmax reduced once per row.
//   Phase B: thread=output column; w from LDS broadcast + coalesced V gather.
__global__ __launch_bounds__(128) void attn1_relu(const float* __restrict__ q1,
                                                  const float* __restrict__ k1,
                                                  const float* __restrict__ v1,
                                                  const int* __restrict__ deg,
                                                  const int* __restrict__ col,
                                                  float* __restrict__ h) {
    int b, i;
    map_bi(blockIdx.x, b, i);
    const int tid = threadIdx.x;

    __shared__ int nbr[MAXDEG];
    __shared__ float qs[128];
    __shared__ float ws[4 * MAXDEG];
    __shared__ int sdeg;

    const size_t stride = (size_t)NN * 128;
    if (tid == 0) sdeg = deg[i];
    qs[tid] = q1[(size_t)b * stride + (size_t)i * 128 + tid];
    __syncthreads();
    const int d = sdeg;
    for (int s = tid; s < d; s += 128) nbr[s] = col[i * MAXDEG + s];
    __syncthreads();

    const float scale = 0.17677669529663687f;   // 1/sqrt(32)
    const int hh = tid >> 5;                    // head 0..3
    const int t  = tid & 31;                    // neighbor slot within round
    const int nr = (d + 31) >> 5;               // rounds (<= 8)

    // q fragment for my head (broadcast LDS reads)
    float4 qv[8];
    #pragma unroll
    for (int kk = 0; kk < 8; ++kk) qv[kk] = *(const float4*)&qs[hh * 32 + kk * 4];

    float sc[8];
    for (int r = 0; r < nr; ++r) {
        const int idx = r * 32 + t;
        float s = -INFINITY;
        if (idx < d) {
            const int j = nbr[idx];
            const float* kr = k1 + (size_t)b * stride + (size_t)j * 128 + hh * 32;
            float acc0 = 0.0f, acc1 = 0.0f;
            #pragma unroll
            for (int kk = 0; kk < 8; kk += 2) {
                const float4 ka = *(const float4*)(kr + kk * 4);
                const float4 kb = *(const float4*)(kr + kk * 4 + 4);
                acc0 = fmaf(qv[kk].x, ka.x, acc0); acc0 = fmaf(qv[kk].y, ka.y, acc0);
                acc0 = fmaf(qv[kk].z, ka.z, acc0); acc0 = fmaf(qv[kk].w, ka.w, acc0);
                acc1 = fmaf(qv[kk+1].x, kb.x, acc1); acc1 = fmaf(qv[kk+1].y, kb.y, acc1);
                acc1 = fmaf(qv[kk+1].z, kb.z, acc1); acc1 = fmaf(qv[kk+1].w, kb.w, acc1);
            }
            s = (acc0 + acc1) * scale;
        }
        sc[r] = s;
    }

    // softmax over (rounds x 32 lanes) within each head group (once per row!)
    float mx = sc[0];
    for (int r = 1; r < nr; ++r) mx = fmaxf(mx, sc[r]);
    #pragma unroll
    for (int off = 16; off >= 1; off >>= 1) mx = fmaxf(mx, __shfl_xor(mx, off));
    float se = 0.0f;
    for (int r = 0; r < nr; ++r) {
        const float e = __expf(sc[r] - mx);     // exp(-inf)=0 for padding
        sc[r] = e;
        se += e;
    }
    #pragma unroll
    for (int off = 16; off >= 1; off >>= 1) se += __shfl_xor(se, off);
    const float inv = (d > 0) ? 1.0f / se : 0.0f;
    for (int r = 0; r < nr; ++r) {
        const int idx = r * 32 + t;
        if (idx < d) ws[hh * MAXDEG + idx] = sc[r] * inv;
    }
    __syncthreads();

    // Phase B: thread = output column c; 4 independent accumulator chains.
    const int c = tid;
    const int h2 = c >> 5;
    const float* __restrict__ vb = v1 + (size_t)b * stride + c;
    const float* __restrict__ wp = ws + h2 * MAXDEG;
    float a0 = 0.0f, a1 = 0.0f, a2 = 0.0f, a3 = 0.0f;
    int t2 = 0;
    for (; t2 + 4 <= d; t2 += 4) {
        const int j0 = nbr[t2], j1 = nbr[t2 + 1], j2 = nbr[t2 + 2], j3 = nbr[t2 + 3];
        a0 = fmaf(wp[t2 + 0], vb[(size_t)j0 * 128], a0);
        a1 = fmaf(wp[t2 + 1], vb[(size_t)j1 * 128], a1);
        a2 = fmaf(wp[t2 + 2], vb[(size_t)j2 * 128], a2);
        a3 = fmaf(wp[t2 + 3], vb[(size_t)j3 * 128], a3);
    }
    for (; t2 < d; ++t2) a0 = fmaf(wp[t2], vb[(size_t)nbr[t2] * 128], a0);
    float o = (a0 + a1) + (a2 + a3);
    if (d == 0) {
        float a = 0.0f;
        for (int j = 0; j < NN; ++j) a += vb[(size_t)j * 128];
        o = a * (1.0f / NN);
    }
    h[(size_t)b * stride + (size_t)i * 128 + c] = fmaxf(o, 0.0f);
}

// ---------------------------------------------------------------------------
// gat2 attention (heads=1, d=64) + residual + LayerNorm. One wave per (b,i),
// same two-phase structure (lane-local 64-dim dot, one softmax reduce).
__global__ __launch_bounds__(64) void attn2_ln(const float* __restrict__ q2,
                                               const float* __restrict__ k2,
                                               const float* __restrict__ v2,
                                               const float* __restrict__ proj,
                                               const int* __restrict__ deg,
                                               const int* __restrict__ col,
                                               const float* __restrict__ gamma,
                                               const float* __restrict__ beta,
                                               float* __restrict__ out) {
    int b, i;
    map_bi(blockIdx.x, b, i);
    const int lane = threadIdx.x;           // 0..63

    __shared__ int nbr[MAXDEG];
    __shared__ float qs[64];
    __shared__ float ws[MAXDEG];
    __shared__ int sdeg;

    const size_t stride = (size_t)NN * 64;
    if (lane == 0) sdeg = deg[i];
    qs[lane] = q2[(size_t)b * stride + (size_t)i * 64 + lane];
    __syncthreads();
    const int d = sdeg;
    for (int s = lane; s < d; s += 64) nbr[s] = col[i * MAXDEG + s];
    __syncthreads();

    const float scale = 0.125f;             // 1/sqrt(64)
    const int nr = (d + 63) >> 6;           // rounds (<= 4)

    float sc[4];
    for (int r = 0; r < nr; ++r) {
        const int idx = r * 64 + lane;
        float s = -INFINITY;
        if (idx < d) {
            const int j = nbr[idx];
            const float* kr = k2 + (size_t)b * stride + (size_t)j * 64;
            float acc0 = 0.0f, acc1 = 0.0f;
            #pragma unroll
            for (int kk = 0; kk < 16; kk += 2) {
                const float4 qa = *(const float4*)&qs[kk * 4];
                const float4 qb = *(const float4*)&qs[kk * 4 + 4];
                const float4 ka = *(const float4*)(kr + kk * 4);
                const float4 kb = *(const float4*)(kr + kk * 4 + 4);
                acc0 = fmaf(qa.x, ka.x, acc0); acc0 = fmaf(qa.y, ka.y, acc0);
                acc0 = fmaf(qa.z, ka.z, acc0); acc0 = fmaf(qa.w, ka.w, acc0);
                acc1 = fmaf(qb.x, kb.x, acc1); acc1 = fmaf(qb.y, kb.y, acc1);
                acc1 = fmaf(qb.z, kb.z, acc1); acc1 = fmaf(qb.w, kb.w, acc1);
            }
            s = (acc0 + acc1) * scale;
        }
        sc[r] = s;
    }

    float mx = sc[0];
    for (int r = 1; r < nr; ++r) mx = fmaxf(mx, sc[r]);
    #pragma unroll
    for (int off = 32; off >= 1; off >>= 1) mx = fmaxf(mx, __shfl_xor(mx, off));
    float se = 0.0f;
    for (int r = 0; r < nr; ++r) {
        const float e = __expf(sc[r] - mx);
        sc[r] = e;
        se += e;
    }
    #pragma unroll
    for (int off = 32; off >= 1; off >>= 1) se += __shfl_xor(se, off);
    const float inv = (d > 0) ? 1.0f / se : 0.0f;
    for (int r = 0; r < nr; ++r) {
        const int idx = r * 64 + lane;
        if (idx < d) ws[idx] = sc[r] * inv;
    }
    __syncthreads();

    // Phase B: thread = column dd.
    const float* __restrict__ vb = v2 + (size_t)b * stride + lane;
    float a0 = 0.0f, a1 = 0.0f, a2 = 0.0f, a3 = 0.0f;
    int t2 = 0;
    for (; t2 + 4 <= d; t2 += 4) {
        const int j0 = nbr[t2], j1 = nbr[t2 + 1], j2 = nbr[t2 + 2], j3 = nbr[t2 + 3];
        a0 = fmaf(ws[t2 + 0], vb[(size_t)j0 * 64], a0);
        a1 = fmaf(ws[t2 + 1], vb[(size_t)j1 * 64], a1);
        a2 = fmaf(ws[t2 + 2], vb[(size_t)j2 * 64], a2);
        a3 = fmaf(ws[t2 + 3], vb[(size_t)j3 * 64], a3);
    }
    for (; t2 < d; ++t2) a0 = fmaf(ws[t2], vb[(size_t)nbr[t2] * 64], a0);
    float att = (a0 + a1) + (a2 + a3);
    if (d == 0) {
        float a = 0.0f;
        for (int j = 0; j < NN; ++j) a += vb[(size_t)j * 64];
        att = a * (1.0f / NN);
    }

    // y = attn_out + proj; LayerNorm over the 64 lanes
    const float y = att + proj[(size_t)b * stride + (size_t)i * 64 + lane];
    float s = y;
    s += __shfl_xor(s, 32); s += __shfl_xor(s, 16); s += __shfl_xor(s, 8);
    s += __shfl_xor(s, 4);  s += __shfl_xor(s, 2);  s += __shfl_xor(s, 1);
    const float mu = s * (1.0f / 64.0f);
    const float yc = y - mu;
    float sq = yc * yc;
    sq += __shfl_xor(sq, 32); sq += __shfl_xor(sq, 16); sq += __shfl_xor(sq, 8);
    sq += __shfl_xor(sq, 4);  sq += __shfl_xor(sq, 2);  sq += __shfl_xor(sq, 1);
    const float var = sq * (1.0f / 64.0f);
    out[(size_t)b * stride + (size_t)i * 64 + lane] =
        gamma[lane] * yc * rsqrtf(var + 1e-6f) + beta[lane];
}

// ---------------------------------------------------------------------------
extern "C" void kernel_launch(void* const* d_in, const int* in_sizes, int n_in,
                              void* d_out, int out_size, void* d_ws, size_t ws_size,
                              hipStream_t stream) {
    const float* x     = (const float*)d_in[0];
    const float* adj   = (const float*)d_in[1];
    const float* Wp    = (const float*)d_in[2];
    const float* bp    = (const float*)d_in[3];
    const float* Wq1   = (const float*)d_in[4];
    const float* bq1   = (const float*)d_in[5];
    const float* Wk1   = (const float*)d_in[6];
    const float* bk1   = (const float*)d_in[7];
    const float* Wv1   = (const float*)d_in[8];
    const float* bv1   = (const float*)d_in[9];
    const float* Wq2   = (const float*)d_in[10];
    const float* bq2   = (const float*)d_in[11];
    const float* Wk2   = (const float*)d_in[12];
    const float* bk2   = (const float*)d_in[13];
    const float* Wv2   = (const float*)d_in[14];
    const float* bv2   = (const float*)d_in[15];
    const float* gamma = (const float*)d_in[16];
    const float* beta  = (const float*)d_in[17];
    float* out = (float*)d_out;

    char* ws = (char*)d_ws;
    size_t off = 0;
    auto alloc = [&](size_t bytes) {
        void* p = ws + off;
        off = (off + bytes + 255) & ~(size_t)255;
        return p;
    };
    int*   deg  = (int*)  alloc((size_t)NN * 4);
    int*   col  = (int*)  alloc((size_t)NN * MAXDEG * 4);
    float* proj = (float*)alloc((size_t)BB * NN * 64 * 4);
    float* q1   = (float*)alloc((size_t)BB * NN * 128 * 4);
    float* k1   = (float*)alloc((size_t)BB * NN * 128 * 4);
    float* v1   = (float*)alloc((size_t)BB * NN * 128 * 4);
    float* h    = (float*)alloc((size_t)BB * NN * 128 * 4);
    float* q2   = (float*)alloc((size_t)BB * NN * 64 * 4);
    float* k2   = (float*)alloc((size_t)BB * NN * 64 * 4);
    float* v2   = (float*)alloc((size_t)BB * NN * 64 * 4);

    build_csr<<<NN, 64, 0, stream>>>(adj, deg, col);

    gemm1_fused<<<BB * NN / 4, 128, 0, stream>>>(x, Wp, bp, Wq1, bq1, Wk1, bk1,
                                                 Wv1, bv1, proj, q1, k1, v1);

    attn1_relu<<<BB * NN, 128, 0, stream>>>(q1, k1, v1, deg, col, h);

    gemm2_fused<<<BB * NN / 8, 192, 0, stream>>>(h, Wq2, bq2, Wk2, bk2, Wv2, bv2,
                                                 q2, k2, v2);

    attn2_ln<<<BB * NN, 64, 0, stream>>>(q2, k2, v2, proj, deg, col, gamma, beta, out);
}

// Round 4
// 71.344 us; speedup vs baseline: 2.6608x; 1.2637x over previous
//
#include <hip/hip_runtime.h>
#include <hip/hip_bf16.h>

// Problem constants (from reference):
//   B=4, N=2048, F_IN=32, D=64; gat1 heads=4 d=32 (out 128); gat2 heads=1 d=64.
#define BB 4
#define NN 2048
#define FIN 32
#define DD 64
#define MAXDEG 256   // binomial(2048, 0.02): mean 41, std 6.3 -> 256 is >30 sigma

// bf16 helpers (ushort-based, RNE pack, shift-unpack)
__device__ __forceinline__ float bflo(unsigned u) { return __uint_as_float(u << 16); }
__device__ __forceinline__ float bfhi(unsigned u) { return __uint_as_float(u & 0xffff0000u); }
__device__ __forceinline__ float bf1(unsigned short s) { return __uint_as_float((unsigned)s << 16); }
__device__ __forceinline__ unsigned short f2bf(float f) {
    union { float f; unsigned u; } x; x.f = f;
    const unsigned r = x.u + 0x7fffu + ((x.u >> 16) & 1u);   // RNE
    return (unsigned short)(r >> 16);
}

// ---------------------------------------------------------------------------
// Fused: CSR build (blocks [0, NN/2), 2 rows/block, one per wave) +
//        K=32 GEMMs proj/q1/k1/v1 (blocks [NN/2, NN/2 + BB*NN/4)).
__global__ __launch_bounds__(128) void csr_gemm1(const float* __restrict__ adj,
    int* __restrict__ deg, int* __restrict__ col,
    const float* __restrict__ x,
    const float* __restrict__ Wp, const float* __restrict__ bp,
    const float* __restrict__ Wq, const float* __restrict__ bq,
    const float* __restrict__ Wk, const float* __restrict__ bk,
    const float* __restrict__ Wv, const float* __restrict__ bv,
    float* __restrict__ proj, float* __restrict__ q1,
    unsigned short* __restrict__ k1, unsigned short* __restrict__ v1) {
    const int bid = blockIdx.x;
    const int tid = threadIdx.x;

    if (bid < NN / 2) {
        // ---- CSR part: wave w handles row 2*bid + w ----
        const int lane = tid & 63;
        const int i = bid * 2 + (tid >> 6);
        const unsigned long long below = (1ull << lane) - 1ull;
        int base = 0;
        for (int j0 = 0; j0 < NN; j0 += 256) {
            const float4 a = *(const float4*)(adj + (size_t)i * NN + j0 + lane * 4);
            const bool n0 = a.x != 0.0f, n1 = a.y != 0.0f, n2 = a.z != 0.0f, n3 = a.w != 0.0f;
            const unsigned long long m0 = __ballot(n0);
            const unsigned long long m1 = __ballot(n1);
            const unsigned long long m2 = __ballot(n2);
            const unsigned long long m3 = __ballot(n3);
            int slot = base + __popcll(m0 & below) + __popcll(m1 & below)
                            + __popcll(m2 & below) + __popcll(m3 & below);
            const int jb = j0 + 4 * lane;
            if (n0) { if (slot < MAXDEG) col[i * MAXDEG + slot] = jb;     ++slot; }
            if (n1) { if (slot < MAXDEG) col[i * MAXDEG + slot] = jb + 1; ++slot; }
            if (n2) { if (slot < MAXDEG) col[i * MAXDEG + slot] = jb + 2; ++slot; }
            if (n3) { if (slot < MAXDEG) col[i * MAXDEG + slot] = jb + 3; ++slot; }
            base += __popcll(m0) + __popcll(m1) + __popcll(m2) + __popcll(m3);
        }
        if (lane == 0) deg[i] = base < MAXDEG ? base : MAXDEG;
        return;
    }

    // ---- GEMM1 part ----
    const int r0 = (bid - NN / 2) * 4;
    __shared__ float xs[FIN * 4];           // xs[k*4+r]
    {
        const int r = tid >> 5, k = tid & 31;
        xs[k * 4 + r] = x[(size_t)r0 * FIN + tid];
    }
    __syncthreads();

    float aq0 = bq[tid], aq1 = aq0, aq2 = aq0, aq3 = aq0;
    float ak0 = bk[tid], ak1 = ak0, ak2 = ak0, ak3 = ak0;
    float av0 = bv[tid], av1 = av0, av2 = av0, av3 = av0;
    #pragma unroll
    for (int k = 0; k < FIN; ++k) {
        const float wq = Wq[k * 128 + tid];
        const float wk = Wk[k * 128 + tid];
        const float wv = Wv[k * 128 + tid];
        const float4 xv = *(const float4*)&xs[k * 4];
        aq0 = fmaf(xv.x, wq, aq0); aq1 = fmaf(xv.y, wq, aq1);
        aq2 = fmaf(xv.z, wq, aq2); aq3 = fmaf(xv.w, wq, aq3);
        ak0 = fmaf(xv.x, wk, ak0); ak1 = fmaf(xv.y, wk, ak1);
        ak2 = fmaf(xv.z, wk, ak2); ak3 = fmaf(xv.w, wk, ak3);
        av0 = fmaf(xv.x, wv, av0); av1 = fmaf(xv.y, wv, av1);
        av2 = fmaf(xv.z, wv, av2); av3 = fmaf(xv.w, wv, av3);
    }
    q1[(size_t)(r0 + 0) * 128 + tid] = aq0; q1[(size_t)(r0 + 1) * 128 + tid] = aq1;
    q1[(size_t)(r0 + 2) * 128 + tid] = aq2; q1[(size_t)(r0 + 3) * 128 + tid] = aq3;
    k1[(size_t)(r0 + 0) * 128 + tid] = f2bf(ak0); k1[(size_t)(r0 + 1) * 128 + tid] = f2bf(ak1);
    k1[(size_t)(r0 + 2) * 128 + tid] = f2bf(ak2); k1[(size_t)(r0 + 3) * 128 + tid] = f2bf(ak3);
    v1[(size_t)(r0 + 0) * 128 + tid] = f2bf(av0); v1[(size_t)(r0 + 1) * 128 + tid] = f2bf(av1);
    v1[(size_t)(r0 + 2) * 128 + tid] = f2bf(av2); v1[(size_t)(r0 + 3) * 128 + tid] = f2bf(av3);

    if (tid < 64) {
        float a0 = bp[tid], a1 = a0, a2 = a0, a3 = a0;
        #pragma unroll
        for (int k = 0; k < FIN; ++k) {
            const float wp = Wp[k * 64 + tid];
            const float4 xv = *(const float4*)&xs[k * 4];
            a0 = fmaf(xv.x, wp, a0); a1 = fmaf(xv.y, wp, a1);
            a2 = fmaf(xv.z, wp, a2); a3 = fmaf(xv.w, wp, a3);
        }
        proj[(size_t)(r0 + 0) * 64 + tid] = a0; proj[(size_t)(r0 + 1) * 64 + tid] = a1;
        proj[(size_t)(r0 + 2) * 64 + tid] = a2; proj[(size_t)(r0 + 3) * 64 + tid] = a3;
    }
}

// ---------------------------------------------------------------------------
// Fused K=128 GEMMs: q2 (fp32) / k2,v2 (bf16). 8 rows/block, 192 threads.
// h input is bf16.
__global__ __launch_bounds__(192) void gemm2_fused(const unsigned short* __restrict__ h,
    const float* __restrict__ Wq, const float* __restrict__ bq,
    const float* __restrict__ Wk, const float* __restrict__ bk,
    const float* __restrict__ Wv, const float* __restrict__ bv,
    float* __restrict__ q2, unsigned short* __restrict__ k2,
    unsigned short* __restrict__ v2) {
    const int r0 = blockIdx.x * 8;
    const int tid = threadIdx.x;
    const int mat = tid / 64;               // wave-uniform
    const int c = tid & 63;
    __shared__ float xs[128][8];            // xs[k][r]
    for (int idx = tid; idx < 8 * 128; idx += 192) {
        const int r = idx >> 7, k = idx & 127;
        xs[k][r] = bf1(h[(size_t)r0 * 128 + idx]);
    }
    __syncthreads();

    const float* __restrict__ W   = mat == 0 ? Wq : (mat == 1 ? Wk : Wv);
    const float* __restrict__ bia = mat == 0 ? bq : (mat == 1 ? bk : bv);

    float acc[8];
    const float b0 = bia[c];
    #pragma unroll
    for (int r = 0; r < 8; ++r) acc[r] = b0;
    #pragma unroll 4
    for (int k = 0; k < 128; ++k) {
        const float w = W[(size_t)k * 64 + c];
        const float4 xa = *(const float4*)&xs[k][0];
        const float4 xb = *(const float4*)&xs[k][4];
        acc[0] = fmaf(xa.x, w, acc[0]); acc[1] = fmaf(xa.y, w, acc[1]);
        acc[2] = fmaf(xa.z, w, acc[2]); acc[3] = fmaf(xa.w, w, acc[3]);
        acc[4] = fmaf(xb.x, w, acc[4]); acc[5] = fmaf(xb.y, w, acc[5]);
        acc[6] = fmaf(xb.z, w, acc[6]); acc[7] = fmaf(xb.w, w, acc[7]);
    }
    if (mat == 0) {
        #pragma unroll
        for (int r = 0; r < 8; ++r) q2[(size_t)(r0 + r) * 64 + c] = acc[r];
    } else {
        unsigned short* __restrict__ Yb = mat == 1 ? k2 : v2;
        #pragma unroll
        for (int r = 0; r < 8; ++r) Yb[(size_t)(r0 + r) * 64 + c] = f2bf(acc[r]);
    }
}

// ---------------------------------------------------------------------------
// XCD-aware (b,i) mapping: 8192 blocks; each XCD (bid&7) handles one batch b.
__device__ __forceinline__ void map_bi(int bid, int& b, int& i) {
    const int xcd = bid & 7;
    const int w = bid >> 3;                 // 0..1023
    b = xcd & 3;
    i = ((xcd >> 2) << 10) | w;
}

// ---------------------------------------------------------------------------
// gat1 attention (heads=4, d=32) + ReLU. Two-phase sparse attention; K/V bf16.
__global__ __launch_bounds__(128) void attn1_relu(const float* __restrict__ q1,
                                                  const unsigned short* __restrict__ k1,
                                                  const unsigned short* __restrict__ v1,
                                                  const int* __restrict__ deg,
                                                  const int* __restrict__ col,
                                                  unsigned short* __restrict__ h) {
    int b, i;
    map_bi(blockIdx.x, b, i);
    const int tid = threadIdx.x;

    __shared__ int nbr[MAXDEG];
    __shared__ float qs[128];
    __shared__ float ws[4 * MAXDEG];
    __shared__ int sdeg;

    const size_t stride = (size_t)NN * 128;
    if (tid == 0) sdeg = deg[i];
    qs[tid] = q1[(size_t)b * stride + (size_t)i * 128 + tid];
    __syncthreads();
    const int d = sdeg;
    for (int s = tid; s < d; s += 128) nbr[s] = col[i * MAXDEG + s];
    __syncthreads();

    const float scale = 0.17677669529663687f;   // 1/sqrt(32)
    const int hh = tid >> 5;                    // head 0..3
    const int t  = tid & 31;                    // neighbor slot within round
    const int nr = (d + 31) >> 5;               // rounds (<= 8)

    // q fragment for my head -> registers
    float qf[32];
    #pragma unroll
    for (int kk = 0; kk < 32; ++kk) qf[kk] = qs[hh * 32 + kk];

    float sc[8];
    for (int r = 0; r < nr; ++r) {
        const int idx = r * 32 + t;
        float s = -INFINITY;
        if (idx < d) {
            const int j = nbr[idx];
            const unsigned short* kr = k1 + (size_t)b * stride + (size_t)j * 128 + hh * 32;
            const uint4* kr4 = (const uint4*)kr;
            float acc0 = 0.0f, acc1 = 0.0f;
            #pragma unroll
            for (int w = 0; w < 4; w += 2) {
                const uint4 ka = kr4[w];
                const uint4 kb = kr4[w + 1];
                const float* qa = &qf[w * 8];
                const float* qb = &qf[w * 8 + 8];
                acc0 = fmaf(qa[0], bflo(ka.x), acc0); acc0 = fmaf(qa[1], bfhi(ka.x), acc0);
                acc0 = fmaf(qa[2], bflo(ka.y), acc0); acc0 = fmaf(qa[3], bfhi(ka.y), acc0);
                acc0 = fmaf(qa[4], bflo(ka.z), acc0); acc0 = fmaf(qa[5], bfhi(ka.z), acc0);
                acc0 = fmaf(qa[6], bflo(ka.w), acc0); acc0 = fmaf(qa[7], bfhi(ka.w), acc0);
                acc1 = fmaf(qb[0], bflo(kb.x), acc1); acc1 = fmaf(qb[1], bfhi(kb.x), acc1);
                acc1 = fmaf(qb[2], bflo(kb.y), acc1); acc1 = fmaf(qb[3], bfhi(kb.y), acc1);
                acc1 = fmaf(qb[4], bflo(kb.z), acc1); acc1 = fmaf(qb[5], bfhi(kb.z), acc1);
                acc1 = fmaf(qb[6], bflo(kb.w), acc1); acc1 = fmaf(qb[7], bfhi(kb.w), acc1);
            }
            s = (acc0 + acc1) * scale;
        }
        sc[r] = s;
    }

    // softmax within each 32-lane head group (once per row)
    float mx = sc[0];
    for (int r = 1; r < nr; ++r) mx = fmaxf(mx, sc[r]);
    #pragma unroll
    for (int off = 16; off >= 1; off >>= 1) mx = fmaxf(mx, __shfl_xor(mx, off));
    float se = 0.0f;
    for (int r = 0; r < nr; ++r) {
        const float e = __expf(sc[r] - mx);     // exp(-inf)=0 for padding
        sc[r] = e;
        se += e;
    }
    #pragma unroll
    for (int off = 16; off >= 1; off >>= 1) se += __shfl_xor(se, off);
    const float inv = (d > 0) ? 1.0f / se : 0.0f;
    for (int r = 0; r < nr; ++r) {
        const int idx = r * 32 + t;
        if (idx < d) ws[hh * MAXDEG + idx] = sc[r] * inv;
    }
    __syncthreads();

    // Phase B: thread = output column c; 4 independent accumulator chains.
    const int c = tid;
    const int h2 = c >> 5;
    const unsigned short* __restrict__ vb = v1 + (size_t)b * stride + c;
    const float* __restrict__ wp = ws + h2 * MAXDEG;
    float a0 = 0.0f, a1 = 0.0f, a2 = 0.0f, a3 = 0.0f;
    int t2 = 0;
    for (; t2 + 4 <= d; t2 += 4) {
        const int j0 = nbr[t2], j1 = nbr[t2 + 1], j2 = nbr[t2 + 2], j3 = nbr[t2 + 3];
        a0 = fmaf(wp[t2 + 0], bf1(vb[(size_t)j0 * 128]), a0);
        a1 = fmaf(wp[t2 + 1], bf1(vb[(size_t)j1 * 128]), a1);
        a2 = fmaf(wp[t2 + 2], bf1(vb[(size_t)j2 * 128]), a2);
        a3 = fmaf(wp[t2 + 3], bf1(vb[(size_t)j3 * 128]), a3);
    }
    for (; t2 < d; ++t2) a0 = fmaf(wp[t2], bf1(vb[(size_t)nbr[t2] * 128]), a0);
    float o = (a0 + a1) + (a2 + a3);
    if (d == 0) {
        float a = 0.0f;
        for (int j = 0; j < NN; ++j) a += bf1(vb[(size_t)j * 128]);
        o = a * (1.0f / NN);
    }
    h[(size_t)b * stride + (size_t)i * 128 + c] = f2bf(fmaxf(o, 0.0f));
}

// ---------------------------------------------------------------------------
// gat2 attention (heads=1, d=64) + residual + LayerNorm. K/V bf16.
__global__ __launch_bounds__(64) void attn2_ln(const float* __restrict__ q2,
                                               const unsigned short* __restrict__ k2,
                                               const unsigned short* __restrict__ v2,
                                               const float* __restrict__ proj,
                                               const int* __restrict__ deg,
                                               const int* __restrict__ col,
                                               const float* __restrict__ gamma,
                                               const float* __restrict__ beta,
                                               float* __restrict__ out) {
    int b, i;
    map_bi(blockIdx.x, b, i);
    const int lane = threadIdx.x;           // 0..63

    __shared__ int nbr[MAXDEG];
    __shared__ float qs[64];
    __shared__ float ws[MAXDEG];
    __shared__ int sdeg;

    const size_t stride = (size_t)NN * 64;
    if (lane == 0) sdeg = deg[i];
    qs[lane] = q2[(size_t)b * stride + (size_t)i * 64 + lane];
    __syncthreads();
    const int d = sdeg;
    for (int s = lane; s < d; s += 64) nbr[s] = col[i * MAXDEG + s];
    __syncthreads();

    const float scale = 0.125f;             // 1/sqrt(64)
    const int nr = (d + 63) >> 6;           // rounds (<= 4)

    float sc[4];
    for (int r = 0; r < nr; ++r) {
        const int idx = r * 64 + lane;
        float s = -INFINITY;
        if (idx < d) {
            const int j = nbr[idx];
            const uint4* kr4 = (const uint4*)(k2 + (size_t)b * stride + (size_t)j * 64);
            float acc0 = 0.0f, acc1 = 0.0f;
            #pragma unroll
            for (int w = 0; w < 8; w += 2) {
                const uint4 ka = kr4[w];
                const uint4 kb = kr4[w + 1];
                const float4 qa0 = *(const float4*)&qs[w * 8];
                const float4 qa1 = *(const float4*)&qs[w * 8 + 4];
                const float4 qb0 = *(const float4*)&qs[w * 8 + 8];
                const float4 qb1 = *(const float4*)&qs[w * 8 + 12];
                acc0 = fmaf(qa0.x, bflo(ka.x), acc0); acc0 = fmaf(qa0.y, bfhi(ka.x), acc0);
                acc0 = fmaf(qa0.z, bflo(ka.y), acc0); acc0 = fmaf(qa0.w, bfhi(ka.y), acc0);
                acc0 = fmaf(qa1.x, bflo(ka.z), acc0); acc0 = fmaf(qa1.y, bfhi(ka.z), acc0);
                acc0 = fmaf(qa1.z, bflo(ka.w), acc0); acc0 = fmaf(qa1.w, bfhi(ka.w), acc0);
                acc1 = fmaf(qb0.x, bflo(kb.x), acc1); acc1 = fmaf(qb0.y, bfhi(kb.x), acc1);
                acc1 = fmaf(qb0.z, bflo(kb.y), acc1); acc1 = fmaf(qb0.w, bfhi(kb.y), acc1);
                acc1 = fmaf(qb1.x, bflo(kb.z), acc1); acc1 = fmaf(qb1.y, bfhi(kb.z), acc1);
                acc1 = fmaf(qb1.z, bflo(kb.w), acc1); acc1 = fmaf(qb1.w, bfhi(kb.w), acc1);
            }
            s = (acc0 + acc1) * scale;
        }
        sc[r] = s;
    }

    float mx = sc[0];
    for (int r = 1; r < nr; ++r) mx = fmaxf(mx, sc[r]);
    #pragma unroll
    for (int off = 32; off >= 1; off >>= 1) mx = fmaxf(mx, __shfl_xor(mx, off));
    float se = 0.0f;
    for (int r = 0; r < nr; ++r) {
        const float e = __expf(sc[r] - mx);
        sc[r] = e;
        se += e;
    }
    #pragma unroll
    for (int off = 32; off >= 1; off >>= 1) se += __shfl_xor(se, off);
    const float inv = (d > 0) ? 1.0f / se : 0.0f;
    for (int r = 0; r < nr; ++r) {
        const int idx = r * 64 + lane;
        if (idx < d) ws[idx] = sc[r] * inv;
    }
    __syncthreads();

    // Phase B: thread = column dd.
    const unsigned short* __restrict__ vb = v2 + (size_t)b * stride + lane;
    float a0 = 0.0f, a1 = 0.0f, a2 = 0.0f, a3 = 0.0f;
    int t2 = 0;
    for (; t2 + 4 <= d; t2 += 4) {
        const int j0 = nbr[t2], j1 = nbr[t2 + 1], j2 = nbr[t2 + 2], j3 = nbr[t2 + 3];
        a0 = fmaf(ws[t2 + 0], bf1(vb[(size_t)j0 * 64]), a0);
        a1 = fmaf(ws[t2 + 1], bf1(vb[(size_t)j1 * 64]), a1);
        a2 = fmaf(ws[t2 + 2], bf1(vb[(size_t)j2 * 64]), a2);
        a3 = fmaf(ws[t2 + 3], bf1(vb[(size_t)j3 * 64]), a3);
    }
    for (; t2 < d; ++t2) a0 = fmaf(ws[t2], bf1(vb[(size_t)nbr[t2] * 64]), a0);
    float att = (a0 + a1) + (a2 + a3);
    if (d == 0) {
        float a = 0.0f;
        for (int j = 0; j < NN; ++j) a += bf1(vb[(size_t)j * 64]);
        att = a * (1.0f / NN);
    }

    // y = attn_out + proj; LayerNorm over the 64 lanes
    const float y = att + proj[(size_t)b * stride + (size_t)i * 64 + lane];
    float s = y;
    s += __shfl_xor(s, 32); s += __shfl_xor(s, 16); s += __shfl_xor(s, 8);
    s += __shfl_xor(s, 4);  s += __shfl_xor(s, 2);  s += __shfl_xor(s, 1);
    const float mu = s * (1.0f / 64.0f);
    const float yc = y - mu;
    float sq = yc * yc;
    sq += __shfl_xor(sq, 32); sq += __shfl_xor(sq, 16); sq += __shfl_xor(sq, 8);
    sq += __shfl_xor(sq, 4);  sq += __shfl_xor(sq, 2);  sq += __shfl_xor(sq, 1);
    const float var = sq * (1.0f / 64.0f);
    out[(size_t)b * stride + (size_t)i * 64 + lane] =
        gamma[lane] * yc * rsqrtf(var + 1e-6f) + beta[lane];
}

// ---------------------------------------------------------------------------
extern "C" void kernel_launch(void* const* d_in, const int* in_sizes, int n_in,
                              void* d_out, int out_size, void* d_ws, size_t ws_size,
                              hipStream_t stream) {
    const float* x     = (const float*)d_in[0];
    const float* adj   = (const float*)d_in[1];
    const float* Wp    = (const float*)d_in[2];
    const float* bp    = (const float*)d_in[3];
    const float* Wq1   = (const float*)d_in[4];
    const float* bq1   = (const float*)d_in[5];
    const float* Wk1   = (const float*)d_in[6];
    const float* bk1   = (const float*)d_in[7];
    const float* Wv1   = (const float*)d_in[8];
    const float* bv1   = (const float*)d_in[9];
    const float* Wq2   = (const float*)d_in[10];
    const float* bq2   = (const float*)d_in[11];
    const float* Wk2   = (const float*)d_in[12];
    const float* bk2   = (const float*)d_in[13];
    const float* Wv2   = (const float*)d_in[14];
    const float* bv2   = (const float*)d_in[15];
    const float* gamma = (const float*)d_in[16];
    const float* beta  = (const float*)d_in[17];
    float* out = (float*)d_out;

    char* ws = (char*)d_ws;
    size_t off = 0;
    auto alloc = [&](size_t bytes) {
        void* p = ws + off;
        off = (off + bytes + 255) & ~(size_t)255;
        return p;
    };
    int*            deg  = (int*)           alloc((size_t)NN * 4);
    int*            col  = (int*)           alloc((size_t)NN * MAXDEG * 4);
    float*          proj = (float*)         alloc((size_t)BB * NN * 64 * 4);
    float*          q1   = (float*)         alloc((size_t)BB * NN * 128 * 4);
    unsigned short* k1   = (unsigned short*)alloc((size_t)BB * NN * 128 * 2);
    unsigned short* v1   = (unsigned short*)alloc((size_t)BB * NN * 128 * 2);
    unsigned short* h    = (unsigned short*)alloc((size_t)BB * NN * 128 * 2);
    float*          q2   = (float*)         alloc((size_t)BB * NN * 64 * 4);
    unsigned short* k2   = (unsigned short*)alloc((size_t)BB * NN * 64 * 2);
    unsigned short* v2   = (unsigned short*)alloc((size_t)BB * NN * 64 * 2);

    csr_gemm1<<<NN / 2 + BB * NN / 4, 128, 0, stream>>>(
        adj, deg, col, x, Wp, bp, Wq1, bq1, Wk1, bk1, Wv1, bv1, proj, q1, k1, v1);

    attn1_relu<<<BB * NN, 128, 0, stream>>>(q1, k1, v1, deg, col, h);

    gemm2_fused<<<BB * NN / 8, 192, 0, stream>>>(h, Wq2, bq2, Wk2, bk2, Wv2, bv2,
                                                 q2, k2, v2);

    attn2_ln<<<BB * NN, 64, 0, stream>>>(q2, k2, v2, proj, deg, col, gamma, beta, out);
}

// Round 5
// 66.232 us; speedup vs baseline: 2.8662x; 1.0772x over previous
//
#include <hip/hip_runtime.h>
#include <hip/hip_bf16.h>
#include <hip/hip_fp16.h>

// Problem constants (from reference):
//   B=4, N=2048, F_IN=32, D=64; gat1 heads=4 d=32 (out 128); gat2 heads=1 d=64.
#define BB 4
#define NN 2048
#define FIN 32
#define DD 64
#define MAXDEG 256   // binomial(2048, 0.02): mean 41, std 6.3 -> 256 is >30 sigma

__device__ __forceinline__ __half2 u2h2(unsigned u) {
    union { unsigned u; __half2 h; } x; x.u = u; return x.h;
}

// ---------------------------------------------------------------------------
// Fused: CSR build (blocks [0, NN/2), 2 rows/block, one per wave) +
//        K=32 GEMMs proj/q1/k1/v1 (blocks [NN/2, NN/2 + BB*NN/4)).
__global__ __launch_bounds__(128) void csr_gemm1(const float* __restrict__ adj,
    int* __restrict__ deg, int* __restrict__ col,
    const float* __restrict__ x,
    const float* __restrict__ Wp, const float* __restrict__ bp,
    const float* __restrict__ Wq, const float* __restrict__ bq,
    const float* __restrict__ Wk, const float* __restrict__ bk,
    const float* __restrict__ Wv, const float* __restrict__ bv,
    float* __restrict__ proj, __half* __restrict__ q1,
    __half* __restrict__ k1, __half* __restrict__ v1) {
    const int bid = blockIdx.x;
    const int tid = threadIdx.x;

    if (bid < NN / 2) {
        // ---- CSR part: wave w handles row 2*bid + w ----
        const int lane = tid & 63;
        const int i = bid * 2 + (tid >> 6);
        const unsigned long long below = (1ull << lane) - 1ull;
        int base = 0;
        for (int j0 = 0; j0 < NN; j0 += 256) {
            const float4 a = *(const float4*)(adj + (size_t)i * NN + j0 + lane * 4);
            const bool n0 = a.x != 0.0f, n1 = a.y != 0.0f, n2 = a.z != 0.0f, n3 = a.w != 0.0f;
            const unsigned long long m0 = __ballot(n0);
            const unsigned long long m1 = __ballot(n1);
            const unsigned long long m2 = __ballot(n2);
            const unsigned long long m3 = __ballot(n3);
            int slot = base + __popcll(m0 & below) + __popcll(m1 & below)
                            + __popcll(m2 & below) + __popcll(m3 & below);
            const int jb = j0 + 4 * lane;
            if (n0) { if (slot < MAXDEG) col[i * MAXDEG + slot] = jb;     ++slot; }
            if (n1) { if (slot < MAXDEG) col[i * MAXDEG + slot] = jb + 1; ++slot; }
            if (n2) { if (slot < MAXDEG) col[i * MAXDEG + slot] = jb + 2; ++slot; }
            if (n3) { if (slot < MAXDEG) col[i * MAXDEG + slot] = jb + 3; ++slot; }
            base += __popcll(m0) + __popcll(m1) + __popcll(m2) + __popcll(m3);
        }
        if (lane == 0) deg[i] = base < MAXDEG ? base : MAXDEG;
        return;
    }

    // ---- GEMM1 part ----
    const int r0 = (bid - NN / 2) * 4;
    __shared__ float xs[FIN * 4];           // xs[k*4+r]
    {
        const int r = tid >> 5, k = tid & 31;
        xs[k * 4 + r] = x[(size_t)r0 * FIN + tid];
    }
    __syncthreads();

    float aq0 = bq[tid], aq1 = aq0, aq2 = aq0, aq3 = aq0;
    float ak0 = bk[tid], ak1 = ak0, ak2 = ak0, ak3 = ak0;
    float av0 = bv[tid], av1 = av0, av2 = av0, av3 = av0;
    #pragma unroll
    for (int k = 0; k < FIN; ++k) {
        const float wq = Wq[k * 128 + tid];
        const float wk = Wk[k * 128 + tid];
        const float wv = Wv[k * 128 + tid];
        const float4 xv = *(const float4*)&xs[k * 4];
        aq0 = fmaf(xv.x, wq, aq0); aq1 = fmaf(xv.y, wq, aq1);
        aq2 = fmaf(xv.z, wq, aq2); aq3 = fmaf(xv.w, wq, aq3);
        ak0 = fmaf(xv.x, wk, ak0); ak1 = fmaf(xv.y, wk, ak1);
        ak2 = fmaf(xv.z, wk, ak2); ak3 = fmaf(xv.w, wk, ak3);
        av0 = fmaf(xv.x, wv, av0); av1 = fmaf(xv.y, wv, av1);
        av2 = fmaf(xv.z, wv, av2); av3 = fmaf(xv.w, wv, av3);
    }
    q1[(size_t)(r0 + 0) * 128 + tid] = __float2half_rn(aq0);
    q1[(size_t)(r0 + 1) * 128 + tid] = __float2half_rn(aq1);
    q1[(size_t)(r0 + 2) * 128 + tid] = __float2half_rn(aq2);
    q1[(size_t)(r0 + 3) * 128 + tid] = __float2half_rn(aq3);
    k1[(size_t)(r0 + 0) * 128 + tid] = __float2half_rn(ak0);
    k1[(size_t)(r0 + 1) * 128 + tid] = __float2half_rn(ak1);
    k1[(size_t)(r0 + 2) * 128 + tid] = __float2half_rn(ak2);
    k1[(size_t)(r0 + 3) * 128 + tid] = __float2half_rn(ak3);
    v1[(size_t)(r0 + 0) * 128 + tid] = __float2half_rn(av0);
    v1[(size_t)(r0 + 1) * 128 + tid] = __float2half_rn(av1);
    v1[(size_t)(r0 + 2) * 128 + tid] = __float2half_rn(av2);
    v1[(size_t)(r0 + 3) * 128 + tid] = __float2half_rn(av3);

    if (tid < 64) {
        float a0 = bp[tid], a1 = a0, a2 = a0, a3 = a0;
        #pragma unroll
        for (int k = 0; k < FIN; ++k) {
            const float wp = Wp[k * 64 + tid];
            const float4 xv = *(const float4*)&xs[k * 4];
            a0 = fmaf(xv.x, wp, a0); a1 = fmaf(xv.y, wp, a1);
            a2 = fmaf(xv.z, wp, a2); a3 = fmaf(xv.w, wp, a3);
        }
        proj[(size_t)(r0 + 0) * 64 + tid] = a0; proj[(size_t)(r0 + 1) * 64 + tid] = a1;
        proj[(size_t)(r0 + 2) * 64 + tid] = a2; proj[(size_t)(r0 + 3) * 64 + tid] = a3;
    }
}

// ---------------------------------------------------------------------------
// Fused K=128 GEMMs: q2/k2/v2 (f16 out). 8 rows/block, 192 threads; h is f16.
__global__ __launch_bounds__(192) void gemm2_fused(const __half* __restrict__ h,
    const float* __restrict__ Wq, const float* __restrict__ bq,
    const float* __restrict__ Wk, const float* __restrict__ bk,
    const float* __restrict__ Wv, const float* __restrict__ bv,
    __half* __restrict__ q2, __half* __restrict__ k2, __half* __restrict__ v2) {
    const int r0 = blockIdx.x * 8;
    const int tid = threadIdx.x;
    const int mat = tid / 64;               // wave-uniform
    const int c = tid & 63;
    __shared__ float xs[128][8];            // xs[k][r]
    for (int idx = tid; idx < 512; idx += 192) {
        const __half2 hv = ((const __half2*)(h + (size_t)r0 * 128))[idx];
        const int flat = idx * 2;
        const int r = flat >> 7, k = flat & 127;
        xs[k][r] = __low2float(hv); xs[k + 1][r] = __high2float(hv);
    }
    __syncthreads();

    const float* __restrict__ W   = mat == 0 ? Wq : (mat == 1 ? Wk : Wv);
    const float* __restrict__ bia = mat == 0 ? bq : (mat == 1 ? bk : bv);
    __half* __restrict__ Y        = mat == 0 ? q2 : (mat == 1 ? k2 : v2);

    float acc[8];
    const float b0 = bia[c];
    #pragma unroll
    for (int r = 0; r < 8; ++r) acc[r] = b0;
    #pragma unroll 4
    for (int k = 0; k < 128; ++k) {
        const float w = W[(size_t)k * 64 + c];
        const float4 xa = *(const float4*)&xs[k][0];
        const float4 xb = *(const float4*)&xs[k][4];
        acc[0] = fmaf(xa.x, w, acc[0]); acc[1] = fmaf(xa.y, w, acc[1]);
        acc[2] = fmaf(xa.z, w, acc[2]); acc[3] = fmaf(xa.w, w, acc[3]);
        acc[4] = fmaf(xb.x, w, acc[4]); acc[5] = fmaf(xb.y, w, acc[5]);
        acc[6] = fmaf(xb.z, w, acc[6]); acc[7] = fmaf(xb.w, w, acc[7]);
    }
    #pragma unroll
    for (int r = 0; r < 8; ++r) Y[(size_t)(r0 + r) * 64 + c] = __float2half_rn(acc[r]);
}

// ---------------------------------------------------------------------------
// XCD-aware (b,i) mapping: 8192 blocks; each XCD (bid&7) handles one batch b.
__device__ __forceinline__ void map_bi(int bid, int& b, int& i) {
    const int xcd = bid & 7;
    const int w = bid >> 3;                 // 0..1023
    b = xcd & 3;
    i = ((xcd >> 2) << 10) | w;
}

// ---------------------------------------------------------------------------
// gat1 attention (heads=4, d=32) + ReLU. Two-phase; f16 K/V, packed-f16 dots.
__global__ __launch_bounds__(128) void attn1_relu(const __half* __restrict__ q1,
                                                  const __half* __restrict__ k1,
                                                  const __half* __restrict__ v1,
                                                  const int* __restrict__ deg,
                                                  const int* __restrict__ col,
                                                  __half* __restrict__ h) {
    int b, i;
    map_bi(blockIdx.x, b, i);
    const int tid = threadIdx.x;

    __shared__ int nbr[MAXDEG];
    __shared__ __half2 qs2[64];             // q row, 128 halves
    __shared__ float wsA[4 * MAXDEG];       // softmax weights per head
    __shared__ float2 part[2][64];          // Phase-B partials per wave
    __shared__ int sdeg;

    const size_t stride = (size_t)NN * 128;
    if (tid == 0) sdeg = deg[i];
    if (tid < 64) qs2[tid] = ((const __half2*)(q1 + (size_t)b * stride + (size_t)i * 128))[tid];
    __syncthreads();
    const int d = sdeg;
    for (int s = tid; s < d; s += 128) nbr[s] = col[i * MAXDEG + s];
    __syncthreads();

    const float scale = 0.17677669529663687f;   // 1/sqrt(32)
    const int hh = tid >> 5;                    // head 0..3
    const int t  = tid & 31;                    // neighbor slot within round
    const int nr = (d + 31) >> 5;               // rounds (<= 8)

    // q fragment for my head -> 16 packed regs
    __half2 qh2[16];
    #pragma unroll
    for (int w = 0; w < 16; ++w) qh2[w] = qs2[hh * 16 + w];

    float sc[8];
    for (int r = 0; r < nr; ++r) {
        const int idx = r * 32 + t;
        float s = -INFINITY;
        if (idx < d) {
            const int j = nbr[idx];
            const uint4* kr4 = (const uint4*)(k1 + (size_t)b * stride + (size_t)j * 128 + hh * 32);
            __half2 a2 = __float2half2_rn(0.0f), b2 = __float2half2_rn(0.0f);
            #pragma unroll
            for (int w = 0; w < 4; ++w) {
                const uint4 kw = kr4[w];
                a2 = __hfma2(qh2[w * 4 + 0], u2h2(kw.x), a2);
                b2 = __hfma2(qh2[w * 4 + 1], u2h2(kw.y), b2);
                a2 = __hfma2(qh2[w * 4 + 2], u2h2(kw.z), a2);
                b2 = __hfma2(qh2[w * 4 + 3], u2h2(kw.w), b2);
            }
            s = ((__low2float(a2) + __high2float(a2)) +
                 (__low2float(b2) + __high2float(b2))) * scale;
        }
        sc[r] = s;
    }

    // softmax within each 32-lane head group (once per row)
    float mx = sc[0];
    for (int r = 1; r < nr; ++r) mx = fmaxf(mx, sc[r]);
    #pragma unroll
    for (int off = 16; off >= 1; off >>= 1) mx = fmaxf(mx, __shfl_xor(mx, off));
    float se = 0.0f;
    for (int r = 0; r < nr; ++r) {
        const float e = __expf(sc[r] - mx);     // exp(-inf)=0 for padding
        sc[r] = e;
        se += e;
    }
    #pragma unroll
    for (int off = 16; off >= 1; off >>= 1) se += __shfl_xor(se, off);
    const float inv = (d > 0) ? 1.0f / se : 0.0f;
    for (int r = 0; r < nr; ++r) {
        const int idx = r * 32 + t;
        if (idx < d) wsA[hh * MAXDEG + idx] = sc[r] * inv;
    }
    __syncthreads();

    // Phase B: lane l owns column pair (2l, 2l+1); waves split the neighbors.
    const int wv = tid >> 6;                // wave 0/1
    const int l  = tid & 63;
    const int hB = l >> 4;                  // head of cols (2l,2l+1)
    const __half* __restrict__ vrow = v1 + (size_t)b * stride + 2 * l;
    const float* __restrict__ wp = wsA + hB * MAXDEG;
    float a0 = 0.0f, a1 = 0.0f, b0 = 0.0f, b1 = 0.0f;
    int t2 = wv;
    for (; t2 + 2 < d; t2 += 4) {
        const int ja = nbr[t2], jb = nbr[t2 + 2];
        const __half2 va = u2h2(*(const unsigned*)(vrow + (size_t)ja * 128));
        const __half2 vb = u2h2(*(const unsigned*)(vrow + (size_t)jb * 128));
        const float wa = wp[t2], wb = wp[t2 + 2];
        a0 = fmaf(wa, __low2float(va), a0); a1 = fmaf(wa, __high2float(va), a1);
        b0 = fmaf(wb, __low2float(vb), b0); b1 = fmaf(wb, __high2float(vb), b1);
    }
    if (t2 < d) {
        const int ja = nbr[t2];
        const __half2 va = u2h2(*(const unsigned*)(vrow + (size_t)ja * 128));
        const float wa = wp[t2];
        a0 = fmaf(wa, __low2float(va), a0); a1 = fmaf(wa, __high2float(va), a1);
    }
    part[wv][l] = make_float2(a0 + b0, a1 + b1);
    __syncthreads();

    if (tid < 64) {
        float o0 = part[0][tid].x + part[1][tid].x;
        float o1 = part[0][tid].y + part[1][tid].y;
        if (d == 0) {
            float s0 = 0.0f, s1 = 0.0f;
            const __half* vr = v1 + (size_t)b * stride + 2 * tid;
            for (int j = 0; j < NN; ++j) {
                const __half2 vj = u2h2(*(const unsigned*)(vr + (size_t)j * 128));
                s0 += __low2float(vj); s1 += __high2float(vj);
            }
            o0 = s0 * (1.0f / NN); o1 = s1 * (1.0f / NN);
        }
        o0 = fmaxf(o0, 0.0f); o1 = fmaxf(o1, 0.0f);
        ((__half2*)(h + (size_t)b * stride + (size_t)i * 128))[tid] =
            __halves2half2(__float2half_rn(o0), __float2half_rn(o1));
    }
}

// ---------------------------------------------------------------------------
// gat2 attention (heads=1, d=64) + residual + LayerNorm. f16 K/V, packed dots.
__global__ __launch_bounds__(64) void attn2_ln(const __half* __restrict__ q2,
                                               const __half* __restrict__ k2,
                                               const __half* __restrict__ v2,
                                               const float* __restrict__ proj,
                                               const int* __restrict__ deg,
                                               const int* __restrict__ col,
                                               const float* __restrict__ gamma,
                                               const float* __restrict__ beta,
                                               float* __restrict__ out) {
    int b, i;
    map_bi(blockIdx.x, b, i);
    const int lane = threadIdx.x;           // 0..63

    __shared__ int nbr[MAXDEG];
    __shared__ __half2 qs2[32];
    __shared__ float wsA[MAXDEG];
    __shared__ float att_lds[64];
    __shared__ int sdeg;

    const size_t stride = (size_t)NN * 64;
    if (lane == 0) sdeg = deg[i];
    if (lane < 32) qs2[lane] = ((const __half2*)(q2 + (size_t)b * stride + (size_t)i * 64))[lane];
    __syncthreads();
    const int d = sdeg;
    for (int s = lane; s < d; s += 64) nbr[s] = col[i * MAXDEG + s];
    __syncthreads();

    const float scale = 0.125f;             // 1/sqrt(64)
    const int nr = (d + 63) >> 6;           // rounds (<= 4)

    __half2 qh2[32];
    #pragma unroll
    for (int w = 0; w < 32; ++w) qh2[w] = qs2[w];

    float sc[4];
    for (int r = 0; r < nr; ++r) {
        const int idx = r * 64 + lane;
        float s = -INFINITY;
        if (idx < d) {
            const int j = nbr[idx];
            const uint4* kr4 = (const uint4*)(k2 + (size_t)b * stride + (size_t)j * 64);
            __half2 a2 = __float2half2_rn(0.0f), b2 = __float2half2_rn(0.0f);
            #pragma unroll
            for (int w = 0; w < 8; ++w) {
                const uint4 kw = kr4[w];
                a2 = __hfma2(qh2[w * 4 + 0], u2h2(kw.x), a2);
                b2 = __hfma2(qh2[w * 4 + 1], u2h2(kw.y), b2);
                a2 = __hfma2(qh2[w * 4 + 2], u2h2(kw.z), a2);
                b2 = __hfma2(qh2[w * 4 + 3], u2h2(kw.w), b2);
            }
            s = ((__low2float(a2) + __high2float(a2)) +
                 (__low2float(b2) + __high2float(b2))) * scale;
        }
        sc[r] = s;
    }

    float mx = sc[0];
    for (int r = 1; r < nr; ++r) mx = fmaxf(mx, sc[r]);
    #pragma unroll
    for (int off = 32; off >= 1; off >>= 1) mx = fmaxf(mx, __shfl_xor(mx, off));
    float se = 0.0f;
    for (int r = 0; r < nr; ++r) {
        const float e = __expf(sc[r] - mx);
        sc[r] = e;
        se += e;
    }
    #pragma unroll
    for (int off = 32; off >= 1; off >>= 1) se += __shfl_xor(se, off);
    const float inv = (d > 0) ? 1.0f / se : 0.0f;
    for (int r = 0; r < nr; ++r) {
        const int idx = r * 64 + lane;
        if (idx < d) wsA[idx] = sc[r] * inv;
    }
    __syncthreads();

    // Phase B: lane = (group g, pair p): cols (2p,2p+1), neighbors t=g,g+2,...
    const int p = lane & 31, g = lane >> 5;
    const __half* __restrict__ vrow = v2 + (size_t)b * stride + 2 * p;
    float a0 = 0.0f, a1 = 0.0f, b0 = 0.0f, b1 = 0.0f;
    int t2 = g;
    for (; t2 + 2 < d; t2 += 4) {
        const int ja = nbr[t2], jb = nbr[t2 + 2];
        const __half2 va = u2h2(*(const unsigned*)(vrow + (size_t)ja * 64));
        const __half2 vb = u2h2(*(const unsigned*)(vrow + (size_t)jb * 64));
        const float wa = wsA[t2], wb = wsA[t2 + 2];
        a0 = fmaf(wa, __low2float(va), a0); a1 = fmaf(wa, __high2float(va), a1);
        b0 = fmaf(wb, __low2float(vb), b0); b1 = fmaf(wb, __high2float(vb), b1);
    }
    if (t2 < d) {
        const int ja = nbr[t2];
        const __half2 va = u2h2(*(const unsigned*)(vrow + (size_t)ja * 64));
        const float wa = wsA[t2];
        a0 = fmaf(wa, __low2float(va), a0); a1 = fmaf(wa, __high2float(va), a1);
    }
    a0 += b0; a1 += b1;
    a0 += __shfl_xor(a0, 32);               // combine the two neighbor groups
    a1 += __shfl_xor(a1, 32);
    if (g == 0) { att_lds[2 * p] = a0; att_lds[2 * p + 1] = a1; }
    __syncthreads();
    float att = att_lds[lane];
    if (d == 0) {
        float a = 0.0f;
        const __half* vr = v2 + (size_t)b * stride + lane;
        for (int j = 0; j < NN; ++j) a += __half2float(vr[(size_t)j * 64]);
        att = a * (1.0f / NN);
    }

    // y = attn_out + proj; LayerNorm over the 64 lanes
    const float y = att + proj[(size_t)b * stride + (size_t)i * 64 + lane];
    float s = y;
    s += __shfl_xor(s, 32); s += __shfl_xor(s, 16); s += __shfl_xor(s, 8);
    s += __shfl_xor(s, 4);  s += __shfl_xor(s, 2);  s += __shfl_xor(s, 1);
    const float mu = s * (1.0f / 64.0f);
    const float yc = y - mu;
    float sq = yc * yc;
    sq += __shfl_xor(sq, 32); sq += __shfl_xor(sq, 16); sq += __shfl_xor(sq, 8);
    sq += __shfl_xor(sq, 4);  sq += __shfl_xor(sq, 2);  sq += __shfl_xor(sq, 1);
    const float var = sq * (1.0f / 64.0f);
    out[(size_t)b * stride + (size_t)i * 64 + lane] =
        gamma[lane] * yc * rsqrtf(var + 1e-6f) + beta[lane];
}

// ---------------------------------------------------------------------------
extern "C" void kernel_launch(void* const* d_in, const int* in_sizes, int n_in,
                              void* d_out, int out_size, void* d_ws, size_t ws_size,
                              hipStream_t stream) {
    const float* x     = (const float*)d_in[0];
    const float* adj   = (const float*)d_in[1];
    const float* Wp    = (const float*)d_in[2];
    const float* bp    = (const float*)d_in[3];
    const float* Wq1   = (const float*)d_in[4];
    const float* bq1   = (const float*)d_in[5];
    const float* Wk1   = (const float*)d_in[6];
    const float* bk1   = (const float*)d_in[7];
    const float* Wv1   = (const float*)d_in[8];
    const float* bv1   = (const float*)d_in[9];
    const float* Wq2   = (const float*)d_in[10];
    const float* bq2   = (const float*)d_in[11];
    const float* Wk2   = (const float*)d_in[12];
    const float* bk2   = (const float*)d_in[13];
    const float* Wv2   = (const float*)d_in[14];
    const float* bv2   = (const float*)d_in[15];
    const float* gamma = (const float*)d_in[16];
    const float* beta  = (const float*)d_in[17];
    float* out = (float*)d_out;

    char* ws = (char*)d_ws;
    size_t off = 0;
    auto alloc = [&](size_t bytes) {
        void* p = ws + off;
        off = (off + bytes + 255) & ~(size_t)255;
        return p;
    };
    int*    deg  = (int*)   alloc((size_t)NN * 4);
    int*    col  = (int*)   alloc((size_t)NN * MAXDEG * 4);
    float*  proj = (float*) alloc((size_t)BB * NN * 64 * 4);
    __half* q1   = (__half*)alloc((size_t)BB * NN * 128 * 2);
    __half* k1   = (__half*)alloc((size_t)BB * NN * 128 * 2);
    __half* v1   = (__half*)alloc((size_t)BB * NN * 128 * 2);
    __half* h    = (__half*)alloc((size_t)BB * NN * 128 * 2);
    __half* q2   = (__half*)alloc((size_t)BB * NN * 64 * 2);
    __half* k2   = (__half*)alloc((size_t)BB * NN * 64 * 2);
    __half* v2   = (__half*)alloc((size_t)BB * NN * 64 * 2);

    csr_gemm1<<<NN / 2 + BB * NN / 4, 128, 0, stream>>>(
        adj, deg, col, x, Wp, bp, Wq1, bq1, Wk1, bk1, Wv1, bv1, proj, q1, k1, v1);

    attn1_relu<<<BB * NN, 128, 0, stream>>>(q1, k1, v1, deg, col, h);

    gemm2_fused<<<BB * NN / 8, 192, 0, stream>>>(h, Wq2, bq2, Wk2, bk2, Wv2, bv2,
                                                 q2, k2, v2);

    attn2_ln<<<BB * NN, 64, 0, stream>>>(q2, k2, v2, proj, deg, col, gamma, beta, out);
}